// Round 1
// 405.075 us; speedup vs baseline: 1.1628x; 1.1628x over previous
//
#include <hip/hip_runtime.h>
#include <math.h>
#include <stdint.h>

// ---------------------------------------------------------------------------
// RadarPillarFeatureNet: N=200000 pillars x M=32 points x C=9 raw channels.
// Float tensor dtype (fp32 vs bf16) is detected at runtime from the bit
// pattern of `features` (k_detect); all compute kernels are instantiated for
// both dtypes and early-exit on a ws flag (uniform branch, graph-safe).
//
// FUSED pipeline (used when ws_size is large enough, ~52 MB):
//   k_detect  : dtype vote -> flag
//   k_prep    : pack MFMA B frags (hi+lo) from weights (no stats needed)
//   k_fused   : ONE pass over features: derive -> LDS -> mfma (hi/lo split in
//               fp32 mode) -> per-pillar per-unit {max,min} of y as fp16x2
//               (51.2 MB) + global Sum(y), Sum(y^2) partials (128 cols)
//   k_reduce2 : column-reduce partials -> 128 doubles
//   k_fin2    : mean/var -> S,T affine
//   k_out     : read {max,min}, out = relu(S>0 ? S*max+T : S*min+T)
// Saves a full 230.4 MB feature re-read vs the two-pass scheme (512->384 MB)
// and deletes the 52-pair moment loop + duplicate derive/pack compute.
//
// FALLBACK (small ws): previous verified two-pass pipeline, unchanged.
// ---------------------------------------------------------------------------

typedef unsigned short u16_t;
typedef __bf16 bf16x8 __attribute__((ext_vector_type(8)));
typedef float floatx16 __attribute__((ext_vector_type(16)));

#define N_P     200000
#define NCHUNK  25000          // N_P / 8 pillars-per-block
#define CNT_TOT 6400000.0      // N*M

__device__ __forceinline__ float bf2f(u16_t u) {
  return __builtin_bit_cast(float, ((unsigned)u) << 16);
}
__device__ __forceinline__ u16_t f2bf(float f) {  // RNE
  unsigned u = __builtin_bit_cast(unsigned, f);
  u += 0x7FFFu + ((u >> 16) & 1u);
  return (u16_t)(u >> 16);
}
__device__ __forceinline__ unsigned pack_h2(float a, float b) {  // fp16 RNE
  unsigned short ua = __builtin_bit_cast(unsigned short, (_Float16)a);
  unsigned short ub = __builtin_bit_cast(unsigned short, (_Float16)b);
  return (unsigned)ua | ((unsigned)ub << 16);
}
__device__ __forceinline__ float h2lo(unsigned u) {
  return (float)__builtin_bit_cast(_Float16, (unsigned short)(u & 0xFFFFu));
}
__device__ __forceinline__ float h2hi(unsigned u) {
  return (float)__builtin_bit_cast(_Float16, (unsigned short)(u >> 16));
}

template<bool BF16>
__device__ __forceinline__ float ldval(const void* p, size_t i) {
  if constexpr (BF16) return bf2f(((const u16_t*)p)[i]);
  else                return ((const float*)p)[i];
}

// 52 within-branch second-moment pairs (fallback path only)
struct Pairs { int pi[52]; int pj[52]; int pa[52]; int pb[52]; };
constexpr Pairs makePairs() {
  Pairs P{};
  int n = 0;
  const int L0[8] = {0, 1, 2, 5, 6, 7, 8, 9};
  for (int a = 0; a < 8; ++a)
    for (int b = a; b < 8; ++b) { P.pi[n]=L0[a]; P.pj[n]=L0[b]; P.pa[n]=a; P.pb[n]=b; ++n; }
  const int L1[2] = {3, 10};
  for (int a = 0; a < 2; ++a)
    for (int b = a; b < 2; ++b) { P.pi[n]=L1[a]; P.pj[n]=L1[b]; P.pa[n]=a; P.pb[n]=b; ++n; }
  const int L2[2] = {4, 11};
  for (int a = 0; a < 2; ++a)
    for (int b = a; b < 2; ++b) { P.pi[n]=L2[a]; P.pj[n]=L2[b]; P.pa[n]=a; P.pb[n]=b; ++n; }
  const int L3[4] = {12, 13, 14, 15};
  for (int a = 0; a < 4; ++a)
    for (int b = a; b < 4; ++b) { P.pi[n]=L3[a]; P.pj[n]=L3[b]; P.pa[n]=a; P.pb[n]=b; ++n; }
  return P;
}
constexpr Pairs PT = makePairs();

// ---------------- dtype detection ------------------------------------------
__global__ void k_detect(const u16_t* __restrict__ f, int* __restrict__ flag) {
  int tid = threadIdx.x;  // 64
  int cnt = 0;
  for (int i = 0; i < 4; ++i) {
    unsigned v = f[(size_t)(tid * 4 + i) * 2];
    unsigned e = (v >> 7) & 0xFF;
    cnt += (e >= 100 && e <= 140) ? 1 : 0;
  }
  for (int s = 1; s < 64; s <<= 1) cnt += __shfl_xor(cnt, s);
  if (tid == 0) *flag = (cnt >= 160) ? 1 : 0;   // 1 == bf16
}

// Derived 16-channel feature for (pillar p, point m).
template<bool BF16>
__device__ __forceinline__ void derive_feat(
    const void* __restrict__ feats, const int* __restrict__ nump,
    const int* __restrict__ coors, int p, int m, float* feat) {
  size_t base = ((size_t)p * 32 + m) * 9;
  float r[9];
#pragma unroll
  for (int c = 0; c < 9; ++c) r[c] = ldval<BF16>(feats, base + c);
  float sx = r[0], sy = r[1], sz = r[2], svx = r[3], svy = r[4];
#pragma unroll
  for (int sft = 1; sft < 32; sft <<= 1) {   // masks <32 stay within 32-lane group
    sx  += __shfl_xor(sx,  sft);
    sy  += __shfl_xor(sy,  sft);
    sz  += __shfl_xor(sz,  sft);
    svx += __shfl_xor(svx, sft);
    svy += __shfl_xor(svy, sft);
  }
  int np = nump[p];
  float inv = 1.0f / (float)np;
  float cx = (float)coors[p * 4 + 3] * 0.2f + 0.1f;
  float cy = (float)coors[p * 4 + 2] * 0.2f - 39.9f;
  feat[0] = r[0] - cx;
  feat[1] = r[1] - cy;
  feat[2] = r[2]; feat[3] = r[3]; feat[4] = r[4];
  feat[5] = r[5]; feat[6] = r[6]; feat[7] = r[7]; feat[8] = r[8];
  feat[9]  = r[0] - sx * inv;
  feat[10] = r[1] - sy * inv;
  feat[11] = r[2] - sz * inv;
  feat[12] = feat[0];
  feat[13] = feat[1];
  feat[14] = r[3] - svx * inv;
  feat[15] = r[4] - svy * inv;
  if (m >= np) {
#pragma unroll
    for (int c = 0; c < 16; ++c) feat[c] = 0.0f;
  }
}

// ---------------- B-fragment helpers ---------------------------------------
template<bool BF16>
__device__ __forceinline__ float wval(int u, int c,
    const void* w1, const void* w2, const void* w3, const void* w4) {
  int b = u >> 4, k = u & 15;
  if (b == 0) {
    int k2 = (c <= 2) ? c : ((c >= 5 && c <= 9) ? c - 2 : -1);
    return (k2 >= 0) ? ldval<BF16>(w1, k * 8 + k2) : 0.0f;
  } else if (b == 1) {
    if (c == 3)  return ldval<BF16>(w2, k * 2 + 0);
    if (c == 10) return ldval<BF16>(w2, k * 2 + 1);
    return 0.0f;
  } else if (b == 2) {
    if (c == 4)  return ldval<BF16>(w3, k * 2 + 0);
    if (c == 11) return ldval<BF16>(w3, k * 2 + 1);
    return 0.0f;
  }
  if (c >= 12) return ldval<BF16>(w4, k * 4 + (c - 12));
  return 0.0f;
}

template<bool BF16>
__device__ __forceinline__ void pack_frags(int u,
    const void* w1, const void* w2, const void* w3, const void* w4,
    uint4* wsB0hi, uint4* wsB0lo, uint4* wsB1hi, uint4* wsB1lo) {
  // B frags for v_mfma_f32_32x32x16_bf16: lane l holds B[k=(l>>5)*8+j][n=l&31]
  int n = u & 31;
  u16_t h0[8], l0[8], h1[8], l1[8];
#pragma unroll
  for (int j = 0; j < 8; ++j) {
    int c = ((u >> 5) << 3) + j;
    float v0 = wval<BF16>(n,      c, w1, w2, w3, w4);
    float v1 = wval<BF16>(n + 32, c, w1, w2, w3, w4);
    h0[j] = f2bf(v0); h1[j] = f2bf(v1);
    l0[j] = BF16 ? (u16_t)0 : f2bf(v0 - bf2f(h0[j]));
    l1[j] = BF16 ? (u16_t)0 : f2bf(v1 - bf2f(h1[j]));
  }
  uint4 a0, a1, c0, c1;
  a0.x = h0[0] | ((unsigned)h0[1] << 16); a0.y = h0[2] | ((unsigned)h0[3] << 16);
  a0.z = h0[4] | ((unsigned)h0[5] << 16); a0.w = h0[6] | ((unsigned)h0[7] << 16);
  c0.x = l0[0] | ((unsigned)l0[1] << 16); c0.y = l0[2] | ((unsigned)l0[3] << 16);
  c0.z = l0[4] | ((unsigned)l0[5] << 16); c0.w = l0[6] | ((unsigned)l0[7] << 16);
  a1.x = h1[0] | ((unsigned)h1[1] << 16); a1.y = h1[2] | ((unsigned)h1[3] << 16);
  a1.z = h1[4] | ((unsigned)h1[5] << 16); a1.w = h1[6] | ((unsigned)h1[7] << 16);
  c1.x = l1[0] | ((unsigned)l1[1] << 16); c1.y = l1[2] | ((unsigned)l1[3] << 16);
  c1.z = l1[4] | ((unsigned)l1[5] << 16); c1.w = l1[6] | ((unsigned)l1[7] << 16);
  wsB0hi[u] = a0; wsB0lo[u] = c0;
  wsB1hi[u] = a1; wsB1lo[u] = c1;
}

// ============================ FUSED PATH ===================================

template<bool BF16>
__global__ void k_prep(const void* __restrict__ w1, const void* __restrict__ w2,
                       const void* __restrict__ w3, const void* __restrict__ w4,
                       const int* __restrict__ flag,
                       uint4* __restrict__ wsB0hi, uint4* __restrict__ wsB0lo,
                       uint4* __restrict__ wsB1hi, uint4* __restrict__ wsB1lo) {
  if (*flag != (BF16 ? 1 : 0)) return;
  pack_frags<BF16>(threadIdx.x, w1, w2, w3, w4, wsB0hi, wsB0lo, wsB1hi, wsB1lo);
}

// One pass: derive -> LDS -> MFMA y -> per-pillar minmax (fp16x2) + stats.
// Each wave's LDS rows are produced AND consumed only by itself (wq=wave*2+q),
// so no __syncthreads in the chunk loop: per-wave in-order DS + compiler
// lgkmcnt handle the RAW hazard; waves run free.
template<bool BF16>
__global__ __launch_bounds__(256) void k_fused(
    const void* __restrict__ feats, const int* __restrict__ nump,
    const int* __restrict__ coors, const int* __restrict__ flag,
    const uint4* __restrict__ wsB0hi, const uint4* __restrict__ wsB0lo,
    const uint4* __restrict__ wsB1hi, const uint4* __restrict__ wsB1lo,
    unsigned* __restrict__ mm, float* __restrict__ part, int g1) {
  if (*flag != (BF16 ? 1 : 0)) return;
  constexpr int TILE = 8 * 32 * 3;           // row stride 3 uint4 spreads banks
  __shared__ uint4 featL[(BF16 ? 1 : 2) * TILE];
  __shared__ float red[4][128];
  int tid = threadIdx.x;
  int wave = tid >> 6, lane = tid & 63;
  int pp = (lane >> 5) & 1, m = lane & 31;

  bf16x8 B0h = __builtin_bit_cast(bf16x8, wsB0hi[lane]);
  bf16x8 B1h = __builtin_bit_cast(bf16x8, wsB1hi[lane]);
  bf16x8 B0l, B1l;
  if constexpr (!BF16) {
    B0l = __builtin_bit_cast(bf16x8, wsB0lo[lane]);
    B1l = __builtin_bit_cast(bf16x8, wsB1lo[lane]);
  }
  floatx16 z;
#pragma unroll
  for (int i = 0; i < 16; ++i) z[i] = 0.0f;

  float sA0 = 0.0f, sQ0 = 0.0f, sA1 = 0.0f, sQ1 = 0.0f;  // Sum y, Sum y^2

  for (int chunk = blockIdx.x; chunk < NCHUNK; chunk += g1) {
    int wp = wave * 2 + pp;
    int p  = chunk * 8 + wp;
    float feat[16];
    derive_feat<BF16>(feats, nump, coors, p, m, feat);

    unsigned pkh[8], pkl[8];
#pragma unroll
    for (int j = 0; j < 8; ++j) {
      float a0 = feat[2 * j], a1 = feat[2 * j + 1];
      u16_t h0 = f2bf(a0), h1 = f2bf(a1);
      pkh[j] = (unsigned)h0 | ((unsigned)h1 << 16);
      if constexpr (!BF16) {
        u16_t q0 = f2bf(a0 - bf2f(h0)), q1 = f2bf(a1 - bf2f(h1));
        pkl[j] = (unsigned)q0 | ((unsigned)q1 << 16);
      }
    }
    uint4 v;
    v.x = pkh[0]; v.y = pkh[1]; v.z = pkh[2]; v.w = pkh[3];
    featL[(wp * 32 + m) * 3 + 0] = v;
    v.x = pkh[4]; v.y = pkh[5]; v.z = pkh[6]; v.w = pkh[7];
    featL[(wp * 32 + m) * 3 + 1] = v;
    if constexpr (!BF16) {
      v.x = pkl[0]; v.y = pkl[1]; v.z = pkl[2]; v.w = pkl[3];
      featL[TILE + (wp * 32 + m) * 3 + 0] = v;
      v.x = pkl[4]; v.y = pkl[5]; v.z = pkl[6]; v.w = pkl[7];
      featL[TILE + (wp * 32 + m) * 3 + 1] = v;
    }

#pragma unroll
    for (int q = 0; q < 2; ++q) {
      int wq = wave * 2 + q;
      int pq = chunk * 8 + wq;
      int ridx = (wq * 32 + (lane & 31)) * 3 + (lane >> 5);
      bf16x8 Ah = __builtin_bit_cast(bf16x8, featL[ridx]);
      floatx16 d0, d1;
      if constexpr (BF16) {
        d0 = __builtin_amdgcn_mfma_f32_32x32x16_bf16(Ah, B0h, z, 0, 0, 0);
        d1 = __builtin_amdgcn_mfma_f32_32x32x16_bf16(Ah, B1h, z, 0, 0, 0);
      } else {
        bf16x8 Al = __builtin_bit_cast(bf16x8, featL[TILE + ridx]);
        d0 = __builtin_amdgcn_mfma_f32_32x32x16_bf16(Al, B0h, z, 0, 0, 0);
        d0 = __builtin_amdgcn_mfma_f32_32x32x16_bf16(Ah, B0l, d0, 0, 0, 0);
        d0 = __builtin_amdgcn_mfma_f32_32x32x16_bf16(Ah, B0h, d0, 0, 0, 0);
        d1 = __builtin_amdgcn_mfma_f32_32x32x16_bf16(Al, B1h, z, 0, 0, 0);
        d1 = __builtin_amdgcn_mfma_f32_32x32x16_bf16(Ah, B1l, d1, 0, 0, 0);
        d1 = __builtin_amdgcn_mfma_f32_32x32x16_bf16(Ah, B1h, d1, 0, 0, 0);
      }
      // D col = lane&31 (unit); 16 regs x 2 lane-halves tile the 32 rows.
      float mx0 = d0[0], mn0 = d0[0], l0s = d0[0], l0q = d0[0] * d0[0];
      float mx1 = d1[0], mn1 = d1[0], l1s = d1[0], l1q = d1[0] * d1[0];
#pragma unroll
      for (int r = 1; r < 16; ++r) {
        float a = d0[r], b = d1[r];
        mx0 = fmaxf(mx0, a); mn0 = fminf(mn0, a);
        l0s += a; l0q = fmaf(a, a, l0q);
        mx1 = fmaxf(mx1, b); mn1 = fminf(mn1, b);
        l1s += b; l1q = fmaf(b, b, l1q);
      }
      sA0 += l0s; sQ0 += l0q; sA1 += l1s; sQ1 += l1q;
      mx0 = fmaxf(mx0, __shfl_xor(mx0, 32));
      mn0 = fminf(mn0, __shfl_xor(mn0, 32));
      mx1 = fmaxf(mx1, __shfl_xor(mx1, 32));
      mn1 = fminf(mn1, __shfl_xor(mn1, 32));
      // lane<32 -> unit lane (d0); lane>=32 -> unit lane (=32+(lane&31), d1)
      unsigned outw = (lane < 32) ? pack_h2(mx0, mn0) : pack_h2(mx1, mn1);
      mm[(size_t)pq * 64 + lane] = outw;
    }
  }

  // block reduce of Sum(y), Sum(y^2): cols 0..63 = Sum y_u, 64..127 = Sum y_u^2
  sA0 += __shfl_xor(sA0, 32); sQ0 += __shfl_xor(sQ0, 32);
  sA1 += __shfl_xor(sA1, 32); sQ1 += __shfl_xor(sQ1, 32);
  if (lane < 32) {
    red[wave][lane]      = sA0;
    red[wave][32 + lane] = sA1;
    red[wave][64 + lane] = sQ0;
    red[wave][96 + lane] = sQ1;
  }
  __syncthreads();
  if (tid < 128)
    part[(size_t)tid * g1 + blockIdx.x] =
        red[0][tid] + red[1][tid] + red[2][tid] + red[3][tid];
}

__global__ void k_reduce2(const float* __restrict__ part,
                          double* __restrict__ mom, int g1) {
  int j = blockIdx.x, tid = threadIdx.x;   // 128 blocks
  double s = 0.0;
  for (int b = tid; b < g1; b += 256) s += (double)part[(size_t)j * g1 + b];
  __shared__ double red[256];
  red[tid] = s;
  __syncthreads();
  for (int off = 128; off; off >>= 1) {
    if (tid < off) red[tid] += red[tid + off];
    __syncthreads();
  }
  if (tid == 0) mom[j] = red[0];
}

template<bool BF16>
__global__ void k_fin2(const double* __restrict__ mom,
                       const void* __restrict__ gamma, const void* __restrict__ beta,
                       const int* __restrict__ flag,
                       float* __restrict__ wsS, float* __restrict__ wsT) {
  if (*flag != (BF16 ? 1 : 0)) return;
  int u = threadIdx.x;  // 64
  double mu  = mom[u] / CNT_TOT;
  double var = mom[64 + u] / CNT_TOT - mu * mu;
  float g  = ldval<BF16>(gamma, u);
  float be = ldval<BF16>(beta, u);
  float S = (float)(1.0 / sqrt(var + 1e-3)) * g;
  float T = be - (float)mu * S;
  wsS[u] = S;
  wsT[u] = T;
}

// out_u = relu(S>0 ? S*max_y + T : S*min_y + T)   (masked rows give y=0,
// already included in minmax). Pure bandwidth: 102.4 MB in/out total.
template<bool BF16>
__global__ __launch_bounds__(256) void k_out(
    const uint4* __restrict__ mm4, const float* __restrict__ wsS,
    const float* __restrict__ wsT, const int* __restrict__ flag,
    void* __restrict__ outv) {
  if (*flag != (BF16 ? 1 : 0)) return;
  __shared__ float sS[64], sT[64];
  int tid = threadIdx.x;
  if (tid < 64) { sS[tid] = wsS[tid]; sT[tid] = wsT[tid]; }
  __syncthreads();
  const int total = N_P * 16;   // uint4 count (4 units each)
  for (int i = blockIdx.x * 256 + tid; i < total; i += gridDim.x * 256) {
    uint4 v = mm4[i];
    unsigned w[4] = {v.x, v.y, v.z, v.w};
    int u0 = (i & 15) * 4;
    float o[4];
#pragma unroll
    for (int j = 0; j < 4; ++j) {
      float mx = h2lo(w[j]), mn = h2hi(w[j]);
      float S = sS[u0 + j], T = sT[u0 + j];
      float zz = (S > 0.0f) ? fmaf(S, mx, T) : fmaf(S, mn, T);
      o[j] = fmaxf(zz, 0.0f);
    }
    if constexpr (BF16) {
      uint2 r;
      r.x = (unsigned)f2bf(o[0]) | ((unsigned)f2bf(o[1]) << 16);
      r.y = (unsigned)f2bf(o[2]) | ((unsigned)f2bf(o[3]) << 16);
      ((uint2*)outv)[i] = r;
    } else {
      float4 f;
      f.x = o[0]; f.y = o[1]; f.z = o[2]; f.w = o[3];
      ((float4*)outv)[i] = f;
    }
  }
}

// ============================ FALLBACK PATH ================================
// (previous verified two-pass pipeline, unchanged)

template<bool BF16>
__global__ void k_moments(const void* __restrict__ feats,
                          const int* __restrict__ nump,
                          const int* __restrict__ coors,
                          const int* __restrict__ flag,
                          float* __restrict__ part, int g1) {
  if (*flag != (BF16 ? 1 : 0)) return;
  int tid = threadIdx.x;
  int wave = tid >> 6, lane = tid & 63;
  int pp = (lane >> 5) & 1, m = lane & 31;
  float acc[68];
#pragma unroll
  for (int i = 0; i < 68; ++i) acc[i] = 0.0f;

  for (int chunk = blockIdx.x; chunk < NCHUNK; chunk += g1) {
    int p = chunk * 8 + wave * 2 + pp;
    float feat[16];
    derive_feat<BF16>(feats, nump, coors, p, m, feat);
#pragma unroll
    for (int c = 0; c < 16; ++c) acc[c] += feat[c];
#pragma unroll
    for (int t = 0; t < 52; ++t)
      acc[16 + t] = fmaf(feat[PT.pi[t]], feat[PT.pj[t]], acc[16 + t]);
  }

#pragma unroll
  for (int k = 0; k < 68; ++k) {
    float v = acc[k];
#pragma unroll
    for (int sft = 1; sft < 64; sft <<= 1) v += __shfl_xor(v, sft);
    acc[k] = v;
  }
  __shared__ float red[4][68];
  if (lane == 0) {
#pragma unroll
    for (int k = 0; k < 68; ++k) red[wave][k] = acc[k];
  }
  __syncthreads();
  if (tid < 68) {
    float t = red[0][tid] + red[1][tid] + red[2][tid] + red[3][tid];
    part[(size_t)tid * g1 + blockIdx.x] = t;
  }
}

__global__ void k_reduce(const float* __restrict__ part,
                         float* __restrict__ mom, int g1) {
  int j = blockIdx.x, tid = threadIdx.x;
  float s = 0.0f;
  for (int b = tid; b < g1; b += 256) s += part[(size_t)j * g1 + b];
  __shared__ float red[256];
  red[tid] = s;
  __syncthreads();
  for (int off = 128; off; off >>= 1) {
    if (tid < off) red[tid] += red[tid + off];
    __syncthreads();
  }
  if (tid == 0) mom[j] = red[0];
}

template<bool BF16>
__global__ void k_finalize(const float* __restrict__ mom,
    const void* __restrict__ w1, const void* __restrict__ w2,
    const void* __restrict__ w3, const void* __restrict__ w4,
    const void* __restrict__ gamma, const void* __restrict__ beta,
    const int* __restrict__ flag,
    float* __restrict__ wsS, float* __restrict__ wsT,
    uint4* __restrict__ wsB0hi, uint4* __restrict__ wsB0lo,
    uint4* __restrict__ wsB1hi, uint4* __restrict__ wsB1lo) {
  if (*flag != (BF16 ? 1 : 0)) return;
  int u = threadIdx.x;  // 0..63
  const int CHOFF[4] = {0, 8, 10, 12};
  const int CCNT[4]  = {8, 2, 2, 4};
  const int LCH[16]  = {0,1,2,5,6,7,8,9, 3,10, 4,11, 12,13,14,15};
  const int PBASE[4] = {0, 36, 39, 42};
  const int PCNTB[4] = {36, 3, 3, 10};

  int b = u >> 4, k = u & 15;
  const void* wsrc = (b == 0) ? w1 : (b == 1) ? w2 : (b == 2) ? w3 : w4;
  int cc = CCNT[b];
  float  w[8];
  double mf[8];
  for (int i = 0; i < 8; ++i) { w[i] = 0.0f; mf[i] = 0.0; }
  for (int i = 0; i < cc; ++i) {
    w[i]  = ldval<BF16>(wsrc, k * cc + i);
    mf[i] = (double)mom[LCH[CHOFF[b] + i]] / CNT_TOT;
  }
  double mu = 0.0;
  for (int i = 0; i < cc; ++i) mu += (double)w[i] * mf[i];
  double var = 0.0;
  for (int t = 0; t < PCNTB[b]; ++t) {
    int idx = PBASE[b] + t;
    int a = PT.pa[idx], b2 = PT.pb[idx];
    double e2  = (double)mom[16 + idx] / CNT_TOT;
    double cov = e2 - mf[a] * mf[b2];
    var += ((a == b2) ? 1.0 : 2.0) * (double)w[a] * (double)w[b2] * cov;
  }
  float g  = ldval<BF16>(gamma, u);
  float be = ldval<BF16>(beta, u);
  float S = (float)(1.0 / sqrt(var + 1e-3)) * g;
  float T = be - (float)mu * S;
  wsS[u] = S;
  wsT[u] = T;

  pack_frags<BF16>(u, w1, w2, w3, w4, wsB0hi, wsB0lo, wsB1hi, wsB1lo);
}

template<bool BF16>
__global__ __launch_bounds__(256) void k_main(
    const void* __restrict__ feats, const int* __restrict__ nump,
    const int* __restrict__ coors, const int* __restrict__ flag,
    const float* __restrict__ wsS, const float* __restrict__ wsT,
    const uint4* __restrict__ wsB0hi, const uint4* __restrict__ wsB0lo,
    const uint4* __restrict__ wsB1hi, const uint4* __restrict__ wsB1lo,
    void* __restrict__ outv) {
  if (*flag != (BF16 ? 1 : 0)) return;
  constexpr int TILE = 8 * 32 * 3;
  __shared__ uint4 featL[(BF16 ? 1 : 2) * TILE];
  int tid = threadIdx.x;
  int wave = tid >> 6, lane = tid & 63;
  int pp = (lane >> 5) & 1, m = lane & 31;

  bf16x8 B0h = __builtin_bit_cast(bf16x8, wsB0hi[lane]);
  bf16x8 B1h = __builtin_bit_cast(bf16x8, wsB1hi[lane]);
  bf16x8 B0l, B1l;
  if constexpr (!BF16) {
    B0l = __builtin_bit_cast(bf16x8, wsB0lo[lane]);
    B1l = __builtin_bit_cast(bf16x8, wsB1lo[lane]);
  }
  int ucol = lane & 31;
  float s0 = wsS[ucol],      t0 = wsT[ucol];
  float s1 = wsS[ucol + 32], t1 = wsT[ucol + 32];

  int wp = wave * 2 + pp;
  int p  = blockIdx.x * 8 + wp;
  float feat[16];
  derive_feat<BF16>(feats, nump, coors, p, m, feat);

  unsigned pkh[8], pkl[8];
#pragma unroll
  for (int j = 0; j < 8; ++j) {
    float a0 = feat[2 * j], a1 = feat[2 * j + 1];
    u16_t h0 = f2bf(a0), h1 = f2bf(a1);
    pkh[j] = (unsigned)h0 | ((unsigned)h1 << 16);
    if constexpr (!BF16) {
      u16_t q0 = f2bf(a0 - bf2f(h0)), q1 = f2bf(a1 - bf2f(h1));
      pkl[j] = (unsigned)q0 | ((unsigned)q1 << 16);
    }
  }
  uint4 v;
  v.x = pkh[0]; v.y = pkh[1]; v.z = pkh[2]; v.w = pkh[3];
  featL[(wp * 32 + m) * 3 + 0] = v;
  v.x = pkh[4]; v.y = pkh[5]; v.z = pkh[6]; v.w = pkh[7];
  featL[(wp * 32 + m) * 3 + 1] = v;
  if constexpr (!BF16) {
    v.x = pkl[0]; v.y = pkl[1]; v.z = pkl[2]; v.w = pkl[3];
    featL[TILE + (wp * 32 + m) * 3 + 0] = v;
    v.x = pkl[4]; v.y = pkl[5]; v.z = pkl[6]; v.w = pkl[7];
    featL[TILE + (wp * 32 + m) * 3 + 1] = v;
  }
  __syncthreads();

  floatx16 z;
#pragma unroll
  for (int i = 0; i < 16; ++i) z[i] = 0.0f;

#pragma unroll
  for (int q = 0; q < 2; ++q) {
    int wq = wave * 2 + q;
    int ridx = (wq * 32 + (lane & 31)) * 3 + (lane >> 5);
    bf16x8 Ah = __builtin_bit_cast(bf16x8, featL[ridx]);
    floatx16 d0, d1;
    if constexpr (BF16) {
      d0 = __builtin_amdgcn_mfma_f32_32x32x16_bf16(Ah, B0h, z, 0, 0, 0);
      d1 = __builtin_amdgcn_mfma_f32_32x32x16_bf16(Ah, B1h, z, 0, 0, 0);
    } else {
      bf16x8 Al = __builtin_bit_cast(bf16x8, featL[TILE + ridx]);
      d0 = __builtin_amdgcn_mfma_f32_32x32x16_bf16(Al, B0h, z, 0, 0, 0);
      d0 = __builtin_amdgcn_mfma_f32_32x32x16_bf16(Ah, B0l, d0, 0, 0, 0);
      d0 = __builtin_amdgcn_mfma_f32_32x32x16_bf16(Ah, B0h, d0, 0, 0, 0);
      d1 = __builtin_amdgcn_mfma_f32_32x32x16_bf16(Al, B1h, z, 0, 0, 0);
      d1 = __builtin_amdgcn_mfma_f32_32x32x16_bf16(Ah, B1l, d1, 0, 0, 0);
      d1 = __builtin_amdgcn_mfma_f32_32x32x16_bf16(Ah, B1h, d1, 0, 0, 0);
    }
    float mx0 = fmaf(d0[0], s0, t0);
    float mx1 = fmaf(d1[0], s1, t1);
#pragma unroll
    for (int r = 1; r < 16; ++r) {
      mx0 = fmaxf(mx0, fmaf(d0[r], s0, t0));
      mx1 = fmaxf(mx1, fmaf(d1[r], s1, t1));
    }
    mx0 = fmaxf(mx0, __shfl_xor(mx0, 32));
    mx1 = fmaxf(mx1, __shfl_xor(mx1, 32));
    mx0 = fmaxf(mx0, 0.0f);
    mx1 = fmaxf(mx1, 0.0f);
    float val = (lane < 32) ? mx0 : mx1;
    size_t oidx = (size_t)(blockIdx.x * 8 + wq) * 64 + lane;
    if constexpr (BF16) ((u16_t*)outv)[oidx] = f2bf(val);
    else                ((float*)outv)[oidx] = val;
  }
}

// ---------------------------------------------------------------------------
extern "C" void kernel_launch(void* const* d_in, const int* in_sizes, int n_in,
                              void* d_out, int out_size, void* d_ws, size_t ws_size,
                              hipStream_t stream) {
  (void)in_sizes; (void)n_in; (void)out_size;
  const void* feats = d_in[0];
  const void* w1    = d_in[1];
  const void* w2    = d_in[2];
  const void* w3    = d_in[3];
  const void* w4    = d_in[4];
  const void* gamma = d_in[5];
  const void* beta  = d_in[6];
  const int*  nump  = (const int*)d_in[7];
  const int*  coors = (const int*)d_in[8];

  char* ws = (char*)d_ws;
  int*   flag   = (int*)(ws + 0);
  float* wsS    = (float*)(ws + 64);      // 64 f32
  float* wsT    = (float*)(ws + 320);     // 64 f32
  uint4* wsB0hi = (uint4*)(ws + 576);     // 64 x 16B
  uint4* wsB0lo = (uint4*)(ws + 1600);
  uint4* wsB1hi = (uint4*)(ws + 2624);
  uint4* wsB1lo = (uint4*)(ws + 3648);

  // fused-path layout
  const int g1f = 1024;
  double*   mom2  = (double*)(ws + 4672);           // 128 doubles -> 5696
  float*    part2 = (float*)(ws + 5696);            // 128*g1f*4 = 524288 -> 529984
  unsigned* mm    = (unsigned*)(ws + 529984);       // N*64*4B = 51.2 MB
  size_t need_fused = 529984ull + (size_t)N_P * 64ull * 4ull;

  if (ws_size >= need_fused) {
    k_detect<<<1, 64, 0, stream>>>((const u16_t*)feats, flag);
    k_prep<true ><<<1, 64, 0, stream>>>(w1, w2, w3, w4, flag, wsB0hi, wsB0lo, wsB1hi, wsB1lo);
    k_prep<false><<<1, 64, 0, stream>>>(w1, w2, w3, w4, flag, wsB0hi, wsB0lo, wsB1hi, wsB1lo);
    k_fused<true ><<<g1f, 256, 0, stream>>>(feats, nump, coors, flag,
                                            wsB0hi, wsB0lo, wsB1hi, wsB1lo, mm, part2, g1f);
    k_fused<false><<<g1f, 256, 0, stream>>>(feats, nump, coors, flag,
                                            wsB0hi, wsB0lo, wsB1hi, wsB1lo, mm, part2, g1f);
    k_reduce2<<<128, 256, 0, stream>>>(part2, mom2, g1f);
    k_fin2<true ><<<1, 64, 0, stream>>>(mom2, gamma, beta, flag, wsS, wsT);
    k_fin2<false><<<1, 64, 0, stream>>>(mom2, gamma, beta, flag, wsS, wsT);
    k_out<true ><<<2048, 256, 0, stream>>>((const uint4*)mm, wsS, wsT, flag, d_out);
    k_out<false><<<2048, 256, 0, stream>>>((const uint4*)mm, wsS, wsT, flag, d_out);
    return;
  }

  // -------- fallback: previous two-pass pipeline --------
  float* mom  = (float*)(ws + 4672);    // 68 f32
  float* part = (float*)(ws + 5120);    // 68 x g1 f32

  int g1 = 1024;
  size_t need = 5120 + (size_t)68 * (size_t)g1 * 4;
  if (need > ws_size) {
    size_t avail = (ws_size > 5120) ? (ws_size - 5120) : 0;
    g1 = (int)(avail / (68 * 4));
    if (g1 > 1024) g1 = 1024;
    if (g1 < 8) g1 = 8;
  }

  k_detect<<<1, 64, 0, stream>>>((const u16_t*)feats, flag);
  k_moments<true ><<<g1, 256, 0, stream>>>(feats, nump, coors, flag, part, g1);
  k_moments<false><<<g1, 256, 0, stream>>>(feats, nump, coors, flag, part, g1);
  k_reduce<<<68, 256, 0, stream>>>(part, mom, g1);
  k_finalize<true ><<<1, 64, 0, stream>>>(mom, w1, w2, w3, w4, gamma, beta, flag,
                                          wsS, wsT, wsB0hi, wsB0lo, wsB1hi, wsB1lo);
  k_finalize<false><<<1, 64, 0, stream>>>(mom, w1, w2, w3, w4, gamma, beta, flag,
                                          wsS, wsT, wsB0hi, wsB0lo, wsB1hi, wsB1lo);
  k_main<true ><<<N_P / 8, 256, 0, stream>>>(feats, nump, coors, flag, wsS, wsT,
                                             wsB0hi, wsB0lo, wsB1hi, wsB1lo, d_out);
  k_main<false><<<N_P / 8, 256, 0, stream>>>(feats, nump, coors, flag, wsS, wsT,
                                             wsB0hi, wsB0lo, wsB1hi, wsB1lo, d_out);
}

// Round 3
// 377.865 us; speedup vs baseline: 1.2465x; 1.0720x over previous
//
#include <hip/hip_runtime.h>
#include <math.h>
#include <stdint.h>

// ---------------------------------------------------------------------------
// RadarPillarFeatureNet: N=200000 pillars x M=32 points x C=9 raw channels.
// dtype (fp32 vs bf16) detected at runtime (k_detect); kernels instantiated
// for both and early-exit on a ws flag (uniform branch, graph-safe).
//
// FUSED pipeline:
//   k_detect  : dtype vote -> flag
//   k_prep    : pack MFMA B frags (hi+lo), columns sign-flipped by sign(gamma)
//   k_fused   : ONE feature pass: derive -> shfl_xor(32) A-frag exchange
//               (NO LDS tile) -> mfma (hi/lo split in fp32 mode) -> per-pillar
//               per-unit max of y' (u16 fp16, 25.6 MB) + Sum(y'),Sum(y'^2)
//   k_reduce2 : column-reduce partials -> 128 doubles
//   k_fin2    : mean/var of y' -> S=|gamma|*rsqrt, T=beta-mu'*S
//   k_out     : out = relu(S*max + T)
// Sign-fold identity: max_m relu(S*y+T) = relu(|S|*max_m(sgn(gamma)*y)+T),
// and stats of y'=sgn*y give identical S,T (|gamma| absorbs the sign).
//
// NOTE: v_permlane32_swap_b32 was tried for the A-frag exchange and FAILED
// correctness (swap direction semantics gamble). The exchange is now done
// with __shfl_xor(...,32) whose semantics are exact; mapping re-derived from
// the verified LDS version: A dword j of pillar q at lane l equals
// H[(l>>5)*4+j] of producer lane (q<<5)|(l&31).
//
// FALLBACK (small ws): two-pass pipeline (wsS stores |S|; B pre-flipped, so
// k_main's max-of-affine stays correct).
// ---------------------------------------------------------------------------

typedef unsigned short u16_t;
typedef __bf16 bf16x8 __attribute__((ext_vector_type(8)));
typedef __bf16 bf16x2_t __attribute__((ext_vector_type(2)));
typedef float floatx16 __attribute__((ext_vector_type(16)));

#define N_P     200000
#define NCHUNK  25000          // N_P / 8 pillars-per-block
#define CNT_TOT 6400000.0      // N*M

__device__ __forceinline__ float bf2f(u16_t u) {
  return __builtin_bit_cast(float, ((unsigned)u) << 16);
}
__device__ __forceinline__ u16_t f2bf(float f) {  // RNE (manual, cold paths)
  unsigned u = __builtin_bit_cast(unsigned, f);
  u += 0x7FFFu + ((u >> 16) & 1u);
  return (u16_t)(u >> 16);
}
// native bf16 pack (v_cvt_pk_bf16_f32 on gfx950), RNE
__device__ __forceinline__ unsigned packbf(float a, float b) {
  bf16x2_t v; v[0] = (__bf16)a; v[1] = (__bf16)b;
  return __builtin_bit_cast(unsigned, v);
}
__device__ __forceinline__ float h2lo(unsigned u) {
  return (float)__builtin_bit_cast(_Float16, (unsigned short)(u & 0xFFFFu));
}
__device__ __forceinline__ float h2hi(unsigned u) {
  return (float)__builtin_bit_cast(_Float16, (unsigned short)(u >> 16));
}

template<bool BF16>
__device__ __forceinline__ float ldval(const void* p, size_t i) {
  if constexpr (BF16) return bf2f(((const u16_t*)p)[i]);
  else                return ((const float*)p)[i];
}

// 52 within-branch second-moment pairs (fallback path only)
struct Pairs { int pi[52]; int pj[52]; int pa[52]; int pb[52]; };
constexpr Pairs makePairs() {
  Pairs P{};
  int n = 0;
  const int L0[8] = {0, 1, 2, 5, 6, 7, 8, 9};
  for (int a = 0; a < 8; ++a)
    for (int b = a; b < 8; ++b) { P.pi[n]=L0[a]; P.pj[n]=L0[b]; P.pa[n]=a; P.pb[n]=b; ++n; }
  const int L1[2] = {3, 10};
  for (int a = 0; a < 2; ++a)
    for (int b = a; b < 2; ++b) { P.pi[n]=L1[a]; P.pj[n]=L1[b]; P.pa[n]=a; P.pb[n]=b; ++n; }
  const int L2[2] = {4, 11};
  for (int a = 0; a < 2; ++a)
    for (int b = a; b < 2; ++b) { P.pi[n]=L2[a]; P.pj[n]=L2[b]; P.pa[n]=a; P.pb[n]=b; ++n; }
  const int L3[4] = {12, 13, 14, 15};
  for (int a = 0; a < 4; ++a)
    for (int b = a; b < 4; ++b) { P.pi[n]=L3[a]; P.pj[n]=L3[b]; P.pa[n]=a; P.pb[n]=b; ++n; }
  return P;
}
constexpr Pairs PT = makePairs();

// ---------------- dtype detection ------------------------------------------
__global__ void k_detect(const u16_t* __restrict__ f, int* __restrict__ flag) {
  int tid = threadIdx.x;  // 64
  int cnt = 0;
  for (int i = 0; i < 4; ++i) {
    unsigned v = f[(size_t)(tid * 4 + i) * 2];
    unsigned e = (v >> 7) & 0xFF;
    cnt += (e >= 100 && e <= 140) ? 1 : 0;
  }
  for (int s = 1; s < 64; s <<= 1) cnt += __shfl_xor(cnt, s);
  if (tid == 0) *flag = (cnt >= 160) ? 1 : 0;   // 1 == bf16
}

// Derived 16-channel feature for (pillar p, point m).
template<bool BF16>
__device__ __forceinline__ void derive_feat(
    const void* __restrict__ feats, const int* __restrict__ nump,
    const int* __restrict__ coors, int p, int m, float* feat) {
  size_t base = ((size_t)p * 32 + m) * 9;
  float r[9];
  if constexpr (BF16) {
#pragma unroll
    for (int c = 0; c < 9; ++c) r[c] = bf2f(((const u16_t*)feats)[base + c]);
  } else {
    // 36B record, 4B aligned: 2x dwordx4 + dword (memcpy keeps align=4 legal)
    const float* fp = (const float*)feats + base;
    float v0[4], v1[4];
    __builtin_memcpy(v0, fp, 16);
    __builtin_memcpy(v1, fp + 4, 16);
    r[0]=v0[0]; r[1]=v0[1]; r[2]=v0[2]; r[3]=v0[3];
    r[4]=v1[0]; r[5]=v1[1]; r[6]=v1[2]; r[7]=v1[3];
    r[8]=fp[8];
  }
  float sx = r[0], sy = r[1], sz = r[2], svx = r[3], svy = r[4];
#pragma unroll
  for (int sft = 1; sft < 32; sft <<= 1) {   // masks <32 stay within 32-lane group
    sx  += __shfl_xor(sx,  sft);
    sy  += __shfl_xor(sy,  sft);
    sz  += __shfl_xor(sz,  sft);
    svx += __shfl_xor(svx, sft);
    svy += __shfl_xor(svy, sft);
  }
  int np = nump[p];
  float inv = 1.0f / (float)np;
  float cx = (float)coors[p * 4 + 3] * 0.2f + 0.1f;
  float cy = (float)coors[p * 4 + 2] * 0.2f - 39.9f;
  feat[0] = r[0] - cx;
  feat[1] = r[1] - cy;
  feat[2] = r[2]; feat[3] = r[3]; feat[4] = r[4];
  feat[5] = r[5]; feat[6] = r[6]; feat[7] = r[7]; feat[8] = r[8];
  feat[9]  = r[0] - sx * inv;
  feat[10] = r[1] - sy * inv;
  feat[11] = r[2] - sz * inv;
  feat[12] = feat[0];
  feat[13] = feat[1];
  feat[14] = r[3] - svx * inv;
  feat[15] = r[4] - svy * inv;
  if (m >= np) {
#pragma unroll
    for (int c = 0; c < 16; ++c) feat[c] = 0.0f;
  }
}

// ---------------- B-fragment helpers ---------------------------------------
template<bool BF16>
__device__ __forceinline__ float wval(int u, int c,
    const void* w1, const void* w2, const void* w3, const void* w4) {
  int b = u >> 4, k = u & 15;
  if (b == 0) {
    int k2 = (c <= 2) ? c : ((c >= 5 && c <= 9) ? c - 2 : -1);
    return (k2 >= 0) ? ldval<BF16>(w1, k * 8 + k2) : 0.0f;
  } else if (b == 1) {
    if (c == 3)  return ldval<BF16>(w2, k * 2 + 0);
    if (c == 10) return ldval<BF16>(w2, k * 2 + 1);
    return 0.0f;
  } else if (b == 2) {
    if (c == 4)  return ldval<BF16>(w3, k * 2 + 0);
    if (c == 11) return ldval<BF16>(w3, k * 2 + 1);
    return 0.0f;
  }
  if (c >= 12) return ldval<BF16>(w4, k * 4 + (c - 12));
  return 0.0f;
}

// B frags for v_mfma_f32_32x32x16_bf16: lane l holds B[k=(l>>5)*8+j][n=l&31].
// Columns pre-multiplied by sign(gamma_n) so downstream needs max only.
template<bool BF16>
__device__ __forceinline__ void pack_frags(int u,
    const void* w1, const void* w2, const void* w3, const void* w4,
    const void* gamma,
    uint4* wsB0hi, uint4* wsB0lo, uint4* wsB1hi, uint4* wsB1lo) {
  int n = u & 31;
  float g0 = ldval<BF16>(gamma, n);
  float g1 = ldval<BF16>(gamma, n + 32);
  float sg0 = (g0 < 0.0f) ? -1.0f : 1.0f;
  float sg1 = (g1 < 0.0f) ? -1.0f : 1.0f;
  u16_t h0[8], l0[8], h1[8], l1[8];
#pragma unroll
  for (int j = 0; j < 8; ++j) {
    int c = ((u >> 5) << 3) + j;
    float v0 = wval<BF16>(n,      c, w1, w2, w3, w4) * sg0;
    float v1 = wval<BF16>(n + 32, c, w1, w2, w3, w4) * sg1;
    h0[j] = f2bf(v0); h1[j] = f2bf(v1);
    l0[j] = BF16 ? (u16_t)0 : f2bf(v0 - bf2f(h0[j]));
    l1[j] = BF16 ? (u16_t)0 : f2bf(v1 - bf2f(h1[j]));
  }
  uint4 a0, a1, c0, c1;
  a0.x = h0[0] | ((unsigned)h0[1] << 16); a0.y = h0[2] | ((unsigned)h0[3] << 16);
  a0.z = h0[4] | ((unsigned)h0[5] << 16); a0.w = h0[6] | ((unsigned)h0[7] << 16);
  c0.x = l0[0] | ((unsigned)l0[1] << 16); c0.y = l0[2] | ((unsigned)l0[3] << 16);
  c0.z = l0[4] | ((unsigned)l0[5] << 16); c0.w = l0[6] | ((unsigned)l0[7] << 16);
  a1.x = h1[0] | ((unsigned)h1[1] << 16); a1.y = h1[2] | ((unsigned)h1[3] << 16);
  a1.z = h1[4] | ((unsigned)h1[5] << 16); a1.w = h1[6] | ((unsigned)h1[7] << 16);
  c1.x = l1[0] | ((unsigned)l1[1] << 16); c1.y = l1[2] | ((unsigned)l1[3] << 16);
  c1.z = l1[4] | ((unsigned)l1[5] << 16); c1.w = l1[6] | ((unsigned)l1[7] << 16);
  wsB0hi[u] = a0; wsB0lo[u] = c0;
  wsB1hi[u] = a1; wsB1lo[u] = c1;
}

// ============================ FUSED PATH ===================================

template<bool BF16>
__global__ void k_prep(const void* __restrict__ w1, const void* __restrict__ w2,
                       const void* __restrict__ w3, const void* __restrict__ w4,
                       const void* __restrict__ gamma,
                       const int* __restrict__ flag,
                       uint4* __restrict__ wsB0hi, uint4* __restrict__ wsB0lo,
                       uint4* __restrict__ wsB1hi, uint4* __restrict__ wsB1lo) {
  if (*flag != (BF16 ? 1 : 0)) return;
  pack_frags<BF16>(threadIdx.x, w1, w2, w3, w4, gamma,
                   wsB0hi, wsB0lo, wsB1hi, wsB1lo);
}

// One pass: derive -> shfl_xor A-frag exchange -> MFMA y' -> max + stats.
// Mapping (from the verified LDS-tile version): A dword j (j=0..3) of
// pillar q at lane l = H[(l>>5)*4+j] of producer lane (q<<5)|(l&31).
// One shuffle per dword: each lane OFFERS what the other half needs
//   pre = lo ? H[4+j] : H[j];  t = shfl_xor(pre, 32)
//   Q0[j] = lo ? H[j] : t      (q=0: own / H[4+j] from l-32)
//   Q1[j] = lo ? t : H[4+j]    (q=1: H[j] from l+32 / own)
template<bool BF16>
__global__ __launch_bounds__(256, 4) void k_fused(
    const void* __restrict__ feats, const int* __restrict__ nump,
    const int* __restrict__ coors, const int* __restrict__ flag,
    const uint4* __restrict__ wsB0hi, const uint4* __restrict__ wsB0lo,
    const uint4* __restrict__ wsB1hi, const uint4* __restrict__ wsB1lo,
    u16_t* __restrict__ mm, float* __restrict__ part, int g1) {
  if (*flag != (BF16 ? 1 : 0)) return;
  __shared__ float red[4][128];
  int tid = threadIdx.x;
  int wave = tid >> 6, lane = tid & 63;
  int pp = (lane >> 5) & 1, m = lane & 31;
  bool lo = (lane < 32);

  bf16x8 B0h = __builtin_bit_cast(bf16x8, wsB0hi[lane]);
  bf16x8 B1h = __builtin_bit_cast(bf16x8, wsB1hi[lane]);
  bf16x8 B0l, B1l;
  if constexpr (!BF16) {
    B0l = __builtin_bit_cast(bf16x8, wsB0lo[lane]);
    B1l = __builtin_bit_cast(bf16x8, wsB1lo[lane]);
  }
  floatx16 z;
#pragma unroll
  for (int i = 0; i < 16; ++i) z[i] = 0.0f;

  float sA0 = 0.0f, sQ0 = 0.0f, sA1 = 0.0f, sQ1 = 0.0f;  // Sum y', Sum y'^2

  for (int chunk = blockIdx.x; chunk < NCHUNK; chunk += g1) {
    int p = chunk * 8 + wave * 2 + pp;
    float feat[16];
    derive_feat<BF16>(feats, nump, coors, p, m, feat);

    unsigned H[8], L[8];
#pragma unroll
    for (int j = 0; j < 8; ++j) {
      float a0 = feat[2 * j], a1 = feat[2 * j + 1];
      __bf16 h0 = (__bf16)a0, h1 = (__bf16)a1;      // v_cvt RNE
      bf16x2_t hv; hv[0] = h0; hv[1] = h1;
      H[j] = __builtin_bit_cast(unsigned, hv);
      if constexpr (!BF16) {
        L[j] = packbf(a0 - (float)h0, a1 - (float)h1);
      }
    }
    unsigned Q0[4], Q1[4], Q0l[4], Q1l[4];
#pragma unroll
    for (int j = 0; j < 4; ++j) {
      unsigned pre = lo ? H[4 + j] : H[j];
      unsigned t = (unsigned)__shfl_xor((int)pre, 32);
      Q0[j] = lo ? H[j] : t;
      Q1[j] = lo ? t : H[4 + j];
      if constexpr (!BF16) {
        unsigned prel = lo ? L[4 + j] : L[j];
        unsigned tl = (unsigned)__shfl_xor((int)prel, 32);
        Q0l[j] = lo ? L[j] : tl;
        Q1l[j] = lo ? tl : L[4 + j];
      }
    }

#pragma unroll
    for (int q = 0; q < 2; ++q) {
      uint4 ah;
      if (q == 0) { ah.x = Q0[0]; ah.y = Q0[1]; ah.z = Q0[2]; ah.w = Q0[3]; }
      else        { ah.x = Q1[0]; ah.y = Q1[1]; ah.z = Q1[2]; ah.w = Q1[3]; }
      bf16x8 Ah = __builtin_bit_cast(bf16x8, ah);
      floatx16 d0, d1;
      if constexpr (BF16) {
        d0 = __builtin_amdgcn_mfma_f32_32x32x16_bf16(Ah, B0h, z, 0, 0, 0);
        d1 = __builtin_amdgcn_mfma_f32_32x32x16_bf16(Ah, B1h, z, 0, 0, 0);
      } else {
        uint4 al;
        if (q == 0) { al.x = Q0l[0]; al.y = Q0l[1]; al.z = Q0l[2]; al.w = Q0l[3]; }
        else        { al.x = Q1l[0]; al.y = Q1l[1]; al.z = Q1l[2]; al.w = Q1l[3]; }
        bf16x8 Al = __builtin_bit_cast(bf16x8, al);
        d0 = __builtin_amdgcn_mfma_f32_32x32x16_bf16(Al, B0h, z, 0, 0, 0);
        d0 = __builtin_amdgcn_mfma_f32_32x32x16_bf16(Ah, B0l, d0, 0, 0, 0);
        d0 = __builtin_amdgcn_mfma_f32_32x32x16_bf16(Ah, B0h, d0, 0, 0, 0);
        d1 = __builtin_amdgcn_mfma_f32_32x32x16_bf16(Al, B1h, z, 0, 0, 0);
        d1 = __builtin_amdgcn_mfma_f32_32x32x16_bf16(Ah, B1l, d1, 0, 0, 0);
        d1 = __builtin_amdgcn_mfma_f32_32x32x16_bf16(Ah, B1h, d1, 0, 0, 0);
      }
      // D col = lane&31 (unit); 16 regs x 2 lane-halves tile the 32 rows.
      float mx0 = d0[0], mx1 = d1[0];
      float l0s = d0[0], l1s = d1[0];
      float l0q = d0[0] * d0[0], l1q = d1[0] * d1[0];
#pragma unroll
      for (int r = 1; r < 15; r += 2) {
        float a = d0[r], a2 = d0[r + 1], b = d1[r], b2 = d1[r + 1];
        mx0 = fmaxf(fmaxf(mx0, a), a2);        // fuses to v_max3_f32
        mx1 = fmaxf(fmaxf(mx1, b), b2);
        l0s += a + a2;  l1s += b + b2;
        l0q = fmaf(a, a, l0q);  l0q = fmaf(a2, a2, l0q);
        l1q = fmaf(b, b, l1q);  l1q = fmaf(b2, b2, l1q);
      }
      {
        float a = d0[15], b = d1[15];
        mx0 = fmaxf(mx0, a); mx1 = fmaxf(mx1, b);
        l0s += a; l1s += b;
        l0q = fmaf(a, a, l0q); l1q = fmaf(b, b, l1q);
      }
      sA0 += l0s; sQ0 += l0q; sA1 += l1s; sQ1 += l1q;
      mx0 = fmaxf(mx0, __shfl_xor(mx0, 32));
      mx1 = fmaxf(mx1, __shfl_xor(mx1, 32));
      float val = lo ? mx0 : mx1;              // unit index == lane
      _Float16 hf = (_Float16)val;
      int pq = chunk * 8 + wave * 2 + q;
      mm[(size_t)pq * 64 + lane] = __builtin_bit_cast(u16_t, hf);
    }
  }

  // block reduce: cols 0..63 = Sum y'_u, 64..127 = Sum y'_u^2
  sA0 += __shfl_xor(sA0, 32); sQ0 += __shfl_xor(sQ0, 32);
  sA1 += __shfl_xor(sA1, 32); sQ1 += __shfl_xor(sQ1, 32);
  if (lane < 32) {
    red[wave][lane]      = sA0;
    red[wave][32 + lane] = sA1;
    red[wave][64 + lane] = sQ0;
    red[wave][96 + lane] = sQ1;
  }
  __syncthreads();
  if (tid < 128)
    part[(size_t)tid * g1 + blockIdx.x] =
        red[0][tid] + red[1][tid] + red[2][tid] + red[3][tid];
}

__global__ void k_reduce2(const float* __restrict__ part,
                          double* __restrict__ mom, int g1) {
  int j = blockIdx.x, tid = threadIdx.x;   // 128 blocks
  double s = 0.0;
  for (int b = tid; b < g1; b += 256) s += (double)part[(size_t)j * g1 + b];
  __shared__ double red[256];
  red[tid] = s;
  __syncthreads();
  for (int off = 128; off; off >>= 1) {
    if (tid < off) red[tid] += red[tid + off];
    __syncthreads();
  }
  if (tid == 0) mom[j] = red[0];
}

template<bool BF16>
__global__ void k_fin2(const double* __restrict__ mom,
                       const void* __restrict__ gamma, const void* __restrict__ beta,
                       const int* __restrict__ flag,
                       float* __restrict__ wsS, float* __restrict__ wsT) {
  if (*flag != (BF16 ? 1 : 0)) return;
  int u = threadIdx.x;  // 64
  double mu  = mom[u] / CNT_TOT;               // mean of y' = sgn*y
  double var = mom[64 + u] / CNT_TOT - mu * mu;
  float g  = ldval<BF16>(gamma, u);
  float be = ldval<BF16>(beta, u);
  float S = (float)(1.0 / sqrt(var + 1e-3)) * fabsf(g);  // |gamma| absorbs sgn
  float T = be - (float)mu * S;
  wsS[u] = S;
  wsT[u] = T;
}

// out_u = relu(S*max + T). 25.6 MB in + out.
template<bool BF16>
__global__ __launch_bounds__(256) void k_out(
    const uint4* __restrict__ mm4, const float* __restrict__ wsS,
    const float* __restrict__ wsT, const int* __restrict__ flag,
    void* __restrict__ outv) {
  if (*flag != (BF16 ? 1 : 0)) return;
  __shared__ float sS[64], sT[64];
  int tid = threadIdx.x;
  if (tid < 64) { sS[tid] = wsS[tid]; sT[tid] = wsT[tid]; }
  __syncthreads();
  const int total = N_P * 8;   // uint4 count (8 units each)
  for (int i = blockIdx.x * 256 + tid; i < total; i += gridDim.x * 256) {
    uint4 v = mm4[i];
    unsigned w[4] = {v.x, v.y, v.z, v.w};
    int u0 = (i & 7) * 8;
    float o[8];
#pragma unroll
    for (int j = 0; j < 4; ++j) {
      float mxa = h2lo(w[j]), mxb = h2hi(w[j]);
      o[2 * j]     = fmaxf(fmaf(sS[u0 + 2 * j],     mxa, sT[u0 + 2 * j]),     0.0f);
      o[2 * j + 1] = fmaxf(fmaf(sS[u0 + 2 * j + 1], mxb, sT[u0 + 2 * j + 1]), 0.0f);
    }
    if constexpr (BF16) {
      uint4 r;
      r.x = packbf(o[0], o[1]); r.y = packbf(o[2], o[3]);
      r.z = packbf(o[4], o[5]); r.w = packbf(o[6], o[7]);
      ((uint4*)outv)[i] = r;
    } else {
      float4 f0, f1;
      f0.x = o[0]; f0.y = o[1]; f0.z = o[2]; f0.w = o[3];
      f1.x = o[4]; f1.y = o[5]; f1.z = o[6]; f1.w = o[7];
      ((float4*)outv)[i * 2]     = f0;
      ((float4*)outv)[i * 2 + 1] = f1;
    }
  }
}

// ============================ FALLBACK PATH ================================
// (two-pass pipeline; wsS = |S| and B pre-flipped keep k_main correct)

template<bool BF16>
__global__ void k_moments(const void* __restrict__ feats,
                          const int* __restrict__ nump,
                          const int* __restrict__ coors,
                          const int* __restrict__ flag,
                          float* __restrict__ part, int g1) {
  if (*flag != (BF16 ? 1 : 0)) return;
  int tid = threadIdx.x;
  int wave = tid >> 6, lane = tid & 63;
  int pp = (lane >> 5) & 1, m = lane & 31;
  float acc[68];
#pragma unroll
  for (int i = 0; i < 68; ++i) acc[i] = 0.0f;

  for (int chunk = blockIdx.x; chunk < NCHUNK; chunk += g1) {
    int p = chunk * 8 + wave * 2 + pp;
    float feat[16];
    derive_feat<BF16>(feats, nump, coors, p, m, feat);
#pragma unroll
    for (int c = 0; c < 16; ++c) acc[c] += feat[c];
#pragma unroll
    for (int t = 0; t < 52; ++t)
      acc[16 + t] = fmaf(feat[PT.pi[t]], feat[PT.pj[t]], acc[16 + t]);
  }

#pragma unroll
  for (int k = 0; k < 68; ++k) {
    float v = acc[k];
#pragma unroll
    for (int sft = 1; sft < 64; sft <<= 1) v += __shfl_xor(v, sft);
    acc[k] = v;
  }
  __shared__ float red[4][68];
  if (lane == 0) {
#pragma unroll
    for (int k = 0; k < 68; ++k) red[wave][k] = acc[k];
  }
  __syncthreads();
  if (tid < 68) {
    float t = red[0][tid] + red[1][tid] + red[2][tid] + red[3][tid];
    part[(size_t)tid * g1 + blockIdx.x] = t;
  }
}

__global__ void k_reduce(const float* __restrict__ part,
                         float* __restrict__ mom, int g1) {
  int j = blockIdx.x, tid = threadIdx.x;
  float s = 0.0f;
  for (int b = tid; b < g1; b += 256) s += part[(size_t)j * g1 + b];
  __shared__ float red[256];
  red[tid] = s;
  __syncthreads();
  for (int off = 128; off; off >>= 1) {
    if (tid < off) red[tid] += red[tid + off];
    __syncthreads();
  }
  if (tid == 0) mom[j] = red[0];
}

template<bool BF16>
__global__ void k_finalize(const float* __restrict__ mom,
    const void* __restrict__ w1, const void* __restrict__ w2,
    const void* __restrict__ w3, const void* __restrict__ w4,
    const void* __restrict__ gamma, const void* __restrict__ beta,
    const int* __restrict__ flag,
    float* __restrict__ wsS, float* __restrict__ wsT,
    uint4* __restrict__ wsB0hi, uint4* __restrict__ wsB0lo,
    uint4* __restrict__ wsB1hi, uint4* __restrict__ wsB1lo) {
  if (*flag != (BF16 ? 1 : 0)) return;
  int u = threadIdx.x;  // 0..63
  const int CHOFF[4] = {0, 8, 10, 12};
  const int CCNT[4]  = {8, 2, 2, 4};
  const int LCH[16]  = {0,1,2,5,6,7,8,9, 3,10, 4,11, 12,13,14,15};
  const int PBASE[4] = {0, 36, 39, 42};
  const int PCNTB[4] = {36, 3, 3, 10};

  int b = u >> 4, k = u & 15;
  const void* wsrc = (b == 0) ? w1 : (b == 1) ? w2 : (b == 2) ? w3 : w4;
  int cc = CCNT[b];
  float  w[8];
  double mf[8];
  for (int i = 0; i < 8; ++i) { w[i] = 0.0f; mf[i] = 0.0; }
  for (int i = 0; i < cc; ++i) {
    w[i]  = ldval<BF16>(wsrc, k * cc + i);
    mf[i] = (double)mom[LCH[CHOFF[b] + i]] / CNT_TOT;
  }
  double mu = 0.0;
  for (int i = 0; i < cc; ++i) mu += (double)w[i] * mf[i];
  double var = 0.0;
  for (int t = 0; t < PCNTB[b]; ++t) {
    int idx = PBASE[b] + t;
    int a = PT.pa[idx], b2 = PT.pb[idx];
    double e2  = (double)mom[16 + idx] / CNT_TOT;
    double cov = e2 - mf[a] * mf[b2];
    var += ((a == b2) ? 1.0 : 2.0) * (double)w[a] * (double)w[b2] * cov;
  }
  float g  = ldval<BF16>(gamma, u);
  float be = ldval<BF16>(beta, u);
  float S = (float)(1.0 / sqrt(var + 1e-3)) * g;
  float T = be - (float)mu * S;
  wsS[u] = fabsf(S);           // |S|: pairs with sign-flipped B frags
  wsT[u] = T;

  pack_frags<BF16>(u, w1, w2, w3, w4, gamma, wsB0hi, wsB0lo, wsB1hi, wsB1lo);
}

template<bool BF16>
__global__ __launch_bounds__(256) void k_main(
    const void* __restrict__ feats, const int* __restrict__ nump,
    const int* __restrict__ coors, const int* __restrict__ flag,
    const float* __restrict__ wsS, const float* __restrict__ wsT,
    const uint4* __restrict__ wsB0hi, const uint4* __restrict__ wsB0lo,
    const uint4* __restrict__ wsB1hi, const uint4* __restrict__ wsB1lo,
    void* __restrict__ outv) {
  if (*flag != (BF16 ? 1 : 0)) return;
  constexpr int TILE = 8 * 32 * 3;
  __shared__ uint4 featL[(BF16 ? 1 : 2) * TILE];
  int tid = threadIdx.x;
  int wave = tid >> 6, lane = tid & 63;
  int pp = (lane >> 5) & 1, m = lane & 31;

  bf16x8 B0h = __builtin_bit_cast(bf16x8, wsB0hi[lane]);
  bf16x8 B1h = __builtin_bit_cast(bf16x8, wsB1hi[lane]);
  bf16x8 B0l, B1l;
  if constexpr (!BF16) {
    B0l = __builtin_bit_cast(bf16x8, wsB0lo[lane]);
    B1l = __builtin_bit_cast(bf16x8, wsB1lo[lane]);
  }
  int ucol = lane & 31;
  float s0 = wsS[ucol],      t0 = wsT[ucol];
  float s1 = wsS[ucol + 32], t1 = wsT[ucol + 32];

  int wp = wave * 2 + pp;
  int p  = blockIdx.x * 8 + wp;
  float feat[16];
  derive_feat<BF16>(feats, nump, coors, p, m, feat);

  unsigned pkh[8], pkl[8];
#pragma unroll
  for (int j = 0; j < 8; ++j) {
    float a0 = feat[2 * j], a1 = feat[2 * j + 1];
    u16_t h0 = f2bf(a0), h1 = f2bf(a1);
    pkh[j] = (unsigned)h0 | ((unsigned)h1 << 16);
    if constexpr (!BF16) {
      u16_t q0 = f2bf(a0 - bf2f(h0)), q1 = f2bf(a1 - bf2f(h1));
      pkl[j] = (unsigned)q0 | ((unsigned)q1 << 16);
    }
  }
  uint4 v;
  v.x = pkh[0]; v.y = pkh[1]; v.z = pkh[2]; v.w = pkh[3];
  featL[(wp * 32 + m) * 3 + 0] = v;
  v.x = pkh[4]; v.y = pkh[5]; v.z = pkh[6]; v.w = pkh[7];
  featL[(wp * 32 + m) * 3 + 1] = v;
  if constexpr (!BF16) {
    v.x = pkl[0]; v.y = pkl[1]; v.z = pkl[2]; v.w = pkl[3];
    featL[TILE + (wp * 32 + m) * 3 + 0] = v;
    v.x = pkl[4]; v.y = pkl[5]; v.z = pkl[6]; v.w = pkl[7];
    featL[TILE + (wp * 32 + m) * 3 + 1] = v;
  }
  __syncthreads();

  floatx16 z;
#pragma unroll
  for (int i = 0; i < 16; ++i) z[i] = 0.0f;

#pragma unroll
  for (int q = 0; q < 2; ++q) {
    int wq = wave * 2 + q;
    int ridx = (wq * 32 + (lane & 31)) * 3 + (lane >> 5);
    bf16x8 Ah = __builtin_bit_cast(bf16x8, featL[ridx]);
    floatx16 d0, d1;
    if constexpr (BF16) {
      d0 = __builtin_amdgcn_mfma_f32_32x32x16_bf16(Ah, B0h, z, 0, 0, 0);
      d1 = __builtin_amdgcn_mfma_f32_32x32x16_bf16(Ah, B1h, z, 0, 0, 0);
    } else {
      bf16x8 Al = __builtin_bit_cast(bf16x8, featL[TILE + ridx]);
      d0 = __builtin_amdgcn_mfma_f32_32x32x16_bf16(Al, B0h, z, 0, 0, 0);
      d0 = __builtin_amdgcn_mfma_f32_32x32x16_bf16(Ah, B0l, d0, 0, 0, 0);
      d0 = __builtin_amdgcn_mfma_f32_32x32x16_bf16(Ah, B0h, d0, 0, 0, 0);
      d1 = __builtin_amdgcn_mfma_f32_32x32x16_bf16(Al, B1h, z, 0, 0, 0);
      d1 = __builtin_amdgcn_mfma_f32_32x32x16_bf16(Ah, B1l, d1, 0, 0, 0);
      d1 = __builtin_amdgcn_mfma_f32_32x32x16_bf16(Ah, B1h, d1, 0, 0, 0);
    }
    float mx0 = fmaf(d0[0], s0, t0);
    float mx1 = fmaf(d1[0], s1, t1);
#pragma unroll
    for (int r = 1; r < 16; ++r) {
      mx0 = fmaxf(mx0, fmaf(d0[r], s0, t0));
      mx1 = fmaxf(mx1, fmaf(d1[r], s1, t1));
    }
    mx0 = fmaxf(mx0, __shfl_xor(mx0, 32));
    mx1 = fmaxf(mx1, __shfl_xor(mx1, 32));
    mx0 = fmaxf(mx0, 0.0f);
    mx1 = fmaxf(mx1, 0.0f);
    float val = (lane < 32) ? mx0 : mx1;
    size_t oidx = (size_t)(blockIdx.x * 8 + wq) * 64 + lane;
    if constexpr (BF16) ((u16_t*)outv)[oidx] = f2bf(val);
    else                ((float*)outv)[oidx] = val;
  }
}

// ---------------------------------------------------------------------------
extern "C" void kernel_launch(void* const* d_in, const int* in_sizes, int n_in,
                              void* d_out, int out_size, void* d_ws, size_t ws_size,
                              hipStream_t stream) {
  (void)in_sizes; (void)n_in; (void)out_size;
  const void* feats = d_in[0];
  const void* w1    = d_in[1];
  const void* w2    = d_in[2];
  const void* w3    = d_in[3];
  const void* w4    = d_in[4];
  const void* gamma = d_in[5];
  const void* beta  = d_in[6];
  const int*  nump  = (const int*)d_in[7];
  const int*  coors = (const int*)d_in[8];

  char* ws = (char*)d_ws;
  int*   flag   = (int*)(ws + 0);
  float* wsS    = (float*)(ws + 64);      // 64 f32
  float* wsT    = (float*)(ws + 320);     // 64 f32
  uint4* wsB0hi = (uint4*)(ws + 576);     // 64 x 16B
  uint4* wsB0lo = (uint4*)(ws + 1600);
  uint4* wsB1hi = (uint4*)(ws + 2624);
  uint4* wsB1lo = (uint4*)(ws + 3648);

  // fused-path layout
  const int g1f = 2048;
  double* mom2  = (double*)(ws + 4672);             // 128 f64 -> 5696
  float*  part2 = (float*)(ws + 5696);              // 128*2048*4 = 1 MiB
  u16_t*  mm    = (u16_t*)(ws + 1054336);           // N*64*2B = 25.6 MB
  size_t need_fused = 1054336ull + (size_t)N_P * 64ull * 2ull;

  if (ws_size >= need_fused) {
    k_detect<<<1, 64, 0, stream>>>((const u16_t*)feats, flag);
    k_prep<true ><<<1, 64, 0, stream>>>(w1, w2, w3, w4, gamma, flag,
                                        wsB0hi, wsB0lo, wsB1hi, wsB1lo);
    k_prep<false><<<1, 64, 0, stream>>>(w1, w2, w3, w4, gamma, flag,
                                        wsB0hi, wsB0lo, wsB1hi, wsB1lo);
    k_fused<true ><<<g1f, 256, 0, stream>>>(feats, nump, coors, flag,
                                            wsB0hi, wsB0lo, wsB1hi, wsB1lo, mm, part2, g1f);
    k_fused<false><<<g1f, 256, 0, stream>>>(feats, nump, coors, flag,
                                            wsB0hi, wsB0lo, wsB1hi, wsB1lo, mm, part2, g1f);
    k_reduce2<<<128, 256, 0, stream>>>(part2, mom2, g1f);
    k_fin2<true ><<<1, 64, 0, stream>>>(mom2, gamma, beta, flag, wsS, wsT);
    k_fin2<false><<<1, 64, 0, stream>>>(mom2, gamma, beta, flag, wsS, wsT);
    k_out<true ><<<2048, 256, 0, stream>>>((const uint4*)mm, wsS, wsT, flag, d_out);
    k_out<false><<<2048, 256, 0, stream>>>((const uint4*)mm, wsS, wsT, flag, d_out);
    return;
  }

  // -------- fallback: two-pass pipeline --------
  float* mom  = (float*)(ws + 4672);    // 68 f32
  float* part = (float*)(ws + 5120);    // 68 x g1 f32

  int g1 = 1024;
  size_t need = 5120 + (size_t)68 * (size_t)g1 * 4;
  if (need > ws_size) {
    size_t avail = (ws_size > 5120) ? (ws_size - 5120) : 0;
    g1 = (int)(avail / (68 * 4));
    if (g1 > 1024) g1 = 1024;
    if (g1 < 8) g1 = 8;
  }

  k_detect<<<1, 64, 0, stream>>>((const u16_t*)feats, flag);
  k_moments<true ><<<g1, 256, 0, stream>>>(feats, nump, coors, flag, part, g1);
  k_moments<false><<<g1, 256, 0, stream>>>(feats, nump, coors, flag, part, g1);
  k_reduce<<<68, 256, 0, stream>>>(part, mom, g1);
  k_finalize<true ><<<1, 64, 0, stream>>>(mom, w1, w2, w3, w4, gamma, beta, flag,
                                          wsS, wsT, wsB0hi, wsB0lo, wsB1hi, wsB1lo);
  k_finalize<false><<<1, 64, 0, stream>>>(mom, w1, w2, w3, w4, gamma, beta, flag,
                                          wsS, wsT, wsB0hi, wsB0lo, wsB1hi, wsB1lo);
  k_main<true ><<<N_P / 8, 256, 0, stream>>>(feats, nump, coors, flag, wsS, wsT,
                                             wsB0hi, wsB0lo, wsB1hi, wsB1lo, d_out);
  k_main<false><<<N_P / 8, 256, 0, stream>>>(feats, nump, coors, flag, wsS, wsT,
                                             wsB0hi, wsB0lo, wsB1hi, wsB1lo, d_out);
}

// Round 4
// 370.133 us; speedup vs baseline: 1.2726x; 1.0209x over previous
//
#include <hip/hip_runtime.h>
#include <math.h>
#include <stdint.h>

// ---------------------------------------------------------------------------
// RadarPillarFeatureNet: N=200000 pillars x M=32 points x C=9 raw channels.
// dtype (fp32 vs bf16) detected at runtime; FUSED path uses runtime-uniform
// flag branches (one kernel per stage, 5 dispatches total).
//
// FUSED pipeline:
//   k_init     : dtype vote -> flag; pack MFMA B frags (hi+lo), columns
//                sign-flipped by sign(gamma)
//   k_fused_all: ONE feature pass, 2-chunk software pipeline (both chunks'
//                global loads issued up front -> latency hidden under the
//                other chunk's compute): derive -> shfl_xor(32) A-frag
//                exchange (no LDS tile) -> mfma (hi/lo split in fp32 mode)
//                -> per-pillar per-unit max of y' (fp16, 25.6 MB)
//                + Sum(y'),Sum(y'^2) partials
//   k_reduce2  : column-reduce partials -> 128 doubles
//   k_fin2_all : mean/var of y' -> S=|gamma|*rsqrt, T=beta-mu'*S
//   k_out_all  : out = relu(S*max + T)
// Sign-fold identity: max_m relu(S*y+T) = relu(|S|*max_m(sgn(gamma)*y)+T);
// stats of y'=sgn*y give identical S,T (|gamma| absorbs the sign).
//
// NOTE: v_permlane32_swap_b32 was tried for the A-frag exchange and FAILED
// correctness (swap-direction semantics gamble). Exchange stays on
// __shfl_xor(...,32): A dword j of pillar q at lane l equals H[(l>>5)*4+j]
// of producer lane (q<<5)|(l&31).
//
// FALLBACK (small ws): original two-pass pipeline (wsS stores |S|; B frags
// pre-flipped, so k_main's max-of-affine stays correct).
// ---------------------------------------------------------------------------

typedef unsigned short u16_t;
typedef __bf16 bf16x8 __attribute__((ext_vector_type(8)));
typedef __bf16 bf16x2_t __attribute__((ext_vector_type(2)));
typedef float floatx16 __attribute__((ext_vector_type(16)));

#define N_P     200000
#define NCHUNK  25000          // N_P / 8 pillars-per-block
#define CNT_TOT 6400000.0      // N*M

__device__ __forceinline__ float bf2f(u16_t u) {
  return __builtin_bit_cast(float, ((unsigned)u) << 16);
}
__device__ __forceinline__ u16_t f2bf(float f) {  // RNE (manual, cold paths)
  unsigned u = __builtin_bit_cast(unsigned, f);
  u += 0x7FFFu + ((u >> 16) & 1u);
  return (u16_t)(u >> 16);
}
// native bf16 pack (v_cvt_pk_bf16_f32 on gfx950), RNE
__device__ __forceinline__ unsigned packbf(float a, float b) {
  bf16x2_t v; v[0] = (__bf16)a; v[1] = (__bf16)b;
  return __builtin_bit_cast(unsigned, v);
}
__device__ __forceinline__ float h2lo(unsigned u) {
  return (float)__builtin_bit_cast(_Float16, (unsigned short)(u & 0xFFFFu));
}
__device__ __forceinline__ float h2hi(unsigned u) {
  return (float)__builtin_bit_cast(_Float16, (unsigned short)(u >> 16));
}

template<bool BF16>
__device__ __forceinline__ float ldval(const void* p, size_t i) {
  if constexpr (BF16) return bf2f(((const u16_t*)p)[i]);
  else                return ((const float*)p)[i];
}

// 52 within-branch second-moment pairs (fallback path only)
struct Pairs { int pi[52]; int pj[52]; int pa[52]; int pb[52]; };
constexpr Pairs makePairs() {
  Pairs P{};
  int n = 0;
  const int L0[8] = {0, 1, 2, 5, 6, 7, 8, 9};
  for (int a = 0; a < 8; ++a)
    for (int b = a; b < 8; ++b) { P.pi[n]=L0[a]; P.pj[n]=L0[b]; P.pa[n]=a; P.pb[n]=b; ++n; }
  const int L1[2] = {3, 10};
  for (int a = 0; a < 2; ++a)
    for (int b = a; b < 2; ++b) { P.pi[n]=L1[a]; P.pj[n]=L1[b]; P.pa[n]=a; P.pb[n]=b; ++n; }
  const int L2[2] = {4, 11};
  for (int a = 0; a < 2; ++a)
    for (int b = a; b < 2; ++b) { P.pi[n]=L2[a]; P.pj[n]=L2[b]; P.pa[n]=a; P.pb[n]=b; ++n; }
  const int L3[4] = {12, 13, 14, 15};
  for (int a = 0; a < 4; ++a)
    for (int b = a; b < 4; ++b) { P.pi[n]=L3[a]; P.pj[n]=L3[b]; P.pa[n]=a; P.pb[n]=b; ++n; }
  return P;
}
constexpr Pairs PT = makePairs();

// ---------------- B-fragment helpers ---------------------------------------
template<bool BF16>
__device__ __forceinline__ float wval(int u, int c,
    const void* w1, const void* w2, const void* w3, const void* w4) {
  int b = u >> 4, k = u & 15;
  if (b == 0) {
    int k2 = (c <= 2) ? c : ((c >= 5 && c <= 9) ? c - 2 : -1);
    return (k2 >= 0) ? ldval<BF16>(w1, k * 8 + k2) : 0.0f;
  } else if (b == 1) {
    if (c == 3)  return ldval<BF16>(w2, k * 2 + 0);
    if (c == 10) return ldval<BF16>(w2, k * 2 + 1);
    return 0.0f;
  } else if (b == 2) {
    if (c == 4)  return ldval<BF16>(w3, k * 2 + 0);
    if (c == 11) return ldval<BF16>(w3, k * 2 + 1);
    return 0.0f;
  }
  if (c >= 12) return ldval<BF16>(w4, k * 4 + (c - 12));
  return 0.0f;
}

// B frags for v_mfma_f32_32x32x16_bf16: lane l holds B[k=(l>>5)*8+j][n=l&31].
// Columns pre-multiplied by sign(gamma_n) so downstream needs max only.
template<bool BF16>
__device__ __forceinline__ void pack_frags(int u,
    const void* w1, const void* w2, const void* w3, const void* w4,
    const void* gamma,
    uint4* wsB0hi, uint4* wsB0lo, uint4* wsB1hi, uint4* wsB1lo) {
  int n = u & 31;
  float g0 = ldval<BF16>(gamma, n);
  float g1 = ldval<BF16>(gamma, n + 32);
  float sg0 = (g0 < 0.0f) ? -1.0f : 1.0f;
  float sg1 = (g1 < 0.0f) ? -1.0f : 1.0f;
  u16_t h0[8], l0[8], h1[8], l1[8];
#pragma unroll
  for (int j = 0; j < 8; ++j) {
    int c = ((u >> 5) << 3) + j;
    float v0 = wval<BF16>(n,      c, w1, w2, w3, w4) * sg0;
    float v1 = wval<BF16>(n + 32, c, w1, w2, w3, w4) * sg1;
    h0[j] = f2bf(v0); h1[j] = f2bf(v1);
    l0[j] = BF16 ? (u16_t)0 : f2bf(v0 - bf2f(h0[j]));
    l1[j] = BF16 ? (u16_t)0 : f2bf(v1 - bf2f(h1[j]));
  }
  uint4 a0, a1, c0, c1;
  a0.x = h0[0] | ((unsigned)h0[1] << 16); a0.y = h0[2] | ((unsigned)h0[3] << 16);
  a0.z = h0[4] | ((unsigned)h0[5] << 16); a0.w = h0[6] | ((unsigned)h0[7] << 16);
  c0.x = l0[0] | ((unsigned)l0[1] << 16); c0.y = l0[2] | ((unsigned)l0[3] << 16);
  c0.z = l0[4] | ((unsigned)l0[5] << 16); c0.w = l0[6] | ((unsigned)l0[7] << 16);
  a1.x = h1[0] | ((unsigned)h1[1] << 16); a1.y = h1[2] | ((unsigned)h1[3] << 16);
  a1.z = h1[4] | ((unsigned)h1[5] << 16); a1.w = h1[6] | ((unsigned)h1[7] << 16);
  c1.x = l1[0] | ((unsigned)l1[1] << 16); c1.y = l1[2] | ((unsigned)l1[3] << 16);
  c1.z = l1[4] | ((unsigned)l1[5] << 16); c1.w = l1[6] | ((unsigned)l1[7] << 16);
  wsB0hi[u] = a0; wsB0lo[u] = c0;
  wsB1hi[u] = a1; wsB1lo[u] = c1;
}

// ============================ FUSED PATH ===================================

// detect dtype + pack B frags in one 64-thread launch (cnt is uniform after
// the 64-lane butterfly, so no barrier needed between flag and pack).
__global__ void k_init(const void* __restrict__ feats,
                       const void* __restrict__ w1, const void* __restrict__ w2,
                       const void* __restrict__ w3, const void* __restrict__ w4,
                       const void* __restrict__ gamma,
                       int* __restrict__ flag,
                       uint4* __restrict__ wsB0hi, uint4* __restrict__ wsB0lo,
                       uint4* __restrict__ wsB1hi, uint4* __restrict__ wsB1lo) {
  const u16_t* f = (const u16_t*)feats;
  int tid = threadIdx.x;  // 64
  int cnt = 0;
  for (int i = 0; i < 4; ++i) {
    unsigned v = f[(size_t)(tid * 4 + i) * 2];
    unsigned e = (v >> 7) & 0xFF;
    cnt += (e >= 100 && e <= 140) ? 1 : 0;
  }
  for (int s = 1; s < 64; s <<= 1) cnt += __shfl_xor(cnt, s);
  int bf = (cnt >= 160) ? 1 : 0;   // 1 == bf16; uniform
  if (tid == 0) *flag = bf;
  if (bf) pack_frags<true >(tid, w1, w2, w3, w4, gamma, wsB0hi, wsB0lo, wsB1hi, wsB1lo);
  else    pack_frags<false>(tid, w1, w2, w3, w4, gamma, wsB0hi, wsB0lo, wsB1hi, wsB1lo);
}

// raw per-(pillar,point) record + pillar-level scalars
struct RawPt {
  float r[9];
  float cx, cy;
  int np;
};

template<bool BF16>
__device__ __forceinline__ RawPt load_raw(
    const void* __restrict__ feats, const int* __restrict__ nump,
    const int* __restrict__ coors, int p, int m) {
  RawPt o;
  size_t base = ((size_t)p * 32 + m) * 9;
  if constexpr (BF16) {
#pragma unroll
    for (int c = 0; c < 9; ++c) o.r[c] = bf2f(((const u16_t*)feats)[base + c]);
  } else {
    // 36B record, 4B aligned: 2x dwordx4 + dword (memcpy keeps align=4 legal)
    const float* fp = (const float*)feats + base;
    float v0[4], v1[4];
    __builtin_memcpy(v0, fp, 16);
    __builtin_memcpy(v1, fp + 4, 16);
    o.r[0]=v0[0]; o.r[1]=v0[1]; o.r[2]=v0[2]; o.r[3]=v0[3];
    o.r[4]=v1[0]; o.r[5]=v1[1]; o.r[6]=v1[2]; o.r[7]=v1[3];
    o.r[8]=fp[8];
  }
  o.np = nump[p];
  o.cx = (float)coors[p * 4 + 3] * 0.2f + 0.1f;
  o.cy = (float)coors[p * 4 + 2] * 0.2f - 39.9f;
  return o;
}

// full per-chunk compute: butterflies -> derive -> pack (masked on packed
// dwords) -> shfl_xor A-frag exchange -> MFMA -> max+stats -> fp16 store.
template<bool BF16>
__device__ __forceinline__ void process_chunk(
    const RawPt& R, int chunk, int wave, int lane, int m, bool lo,
    const bf16x8& B0h, const bf16x8& B1h, const bf16x8& B0l, const bf16x8& B1l,
    u16_t* __restrict__ mm,
    float& sA0, float& sQ0, float& sA1, float& sQ1) {
  float sx = R.r[0], sy = R.r[1], sz = R.r[2], svx = R.r[3], svy = R.r[4];
#pragma unroll
  for (int sft = 1; sft < 32; sft <<= 1) {   // masks <32 stay within 32-lane group
    sx  += __shfl_xor(sx,  sft);
    sy  += __shfl_xor(sy,  sft);
    sz  += __shfl_xor(sz,  sft);
    svx += __shfl_xor(svx, sft);
    svy += __shfl_xor(svy, sft);
  }
  float inv = 1.0f / (float)R.np;
  float feat[16];
  feat[0] = R.r[0] - R.cx;
  feat[1] = R.r[1] - R.cy;
  feat[2] = R.r[2]; feat[3] = R.r[3]; feat[4] = R.r[4];
  feat[5] = R.r[5]; feat[6] = R.r[6]; feat[7] = R.r[7]; feat[8] = R.r[8];
  feat[9]  = R.r[0] - sx * inv;
  feat[10] = R.r[1] - sy * inv;
  feat[11] = R.r[2] - sz * inv;
  feat[12] = feat[0];
  feat[13] = feat[1];
  feat[14] = R.r[3] - svx * inv;
  feat[15] = R.r[4] - svy * inv;
  bool valid = (m < R.np);

  unsigned H[8], L[8];
#pragma unroll
  for (int j = 0; j < 8; ++j) {
    float a0 = feat[2 * j], a1 = feat[2 * j + 1];
    __bf16 h0 = (__bf16)a0, h1 = (__bf16)a1;      // v_cvt RNE
    bf16x2_t hv; hv[0] = h0; hv[1] = h1;
    unsigned hw = __builtin_bit_cast(unsigned, hv);
    H[j] = valid ? hw : 0u;                       // mask packed dword
    if constexpr (!BF16) {
      unsigned lw = packbf(a0 - (float)h0, a1 - (float)h1);
      L[j] = valid ? lw : 0u;
    }
  }
  // A-frag exchange: A dword j of pillar q at lane l = H[(l>>5)*4+j] of
  // producer lane (q<<5)|(l&31). One shfl per dword (offer-what-other-needs).
  unsigned Q0[4], Q1[4], Q0l[4], Q1l[4];
#pragma unroll
  for (int j = 0; j < 4; ++j) {
    unsigned pre = lo ? H[4 + j] : H[j];
    unsigned t = (unsigned)__shfl_xor((int)pre, 32);
    Q0[j] = lo ? H[j] : t;
    Q1[j] = lo ? t : H[4 + j];
    if constexpr (!BF16) {
      unsigned prel = lo ? L[4 + j] : L[j];
      unsigned tl = (unsigned)__shfl_xor((int)prel, 32);
      Q0l[j] = lo ? L[j] : tl;
      Q1l[j] = lo ? tl : L[4 + j];
    }
  }

  floatx16 z;
#pragma unroll
  for (int i = 0; i < 16; ++i) z[i] = 0.0f;

#pragma unroll
  for (int q = 0; q < 2; ++q) {
    uint4 ah;
    if (q == 0) { ah.x = Q0[0]; ah.y = Q0[1]; ah.z = Q0[2]; ah.w = Q0[3]; }
    else        { ah.x = Q1[0]; ah.y = Q1[1]; ah.z = Q1[2]; ah.w = Q1[3]; }
    bf16x8 Ah = __builtin_bit_cast(bf16x8, ah);
    floatx16 d0, d1;
    if constexpr (BF16) {
      d0 = __builtin_amdgcn_mfma_f32_32x32x16_bf16(Ah, B0h, z, 0, 0, 0);
      d1 = __builtin_amdgcn_mfma_f32_32x32x16_bf16(Ah, B1h, z, 0, 0, 0);
    } else {
      uint4 al;
      if (q == 0) { al.x = Q0l[0]; al.y = Q0l[1]; al.z = Q0l[2]; al.w = Q0l[3]; }
      else        { al.x = Q1l[0]; al.y = Q1l[1]; al.z = Q1l[2]; al.w = Q1l[3]; }
      bf16x8 Al = __builtin_bit_cast(bf16x8, al);
      d0 = __builtin_amdgcn_mfma_f32_32x32x16_bf16(Al, B0h, z, 0, 0, 0);
      d0 = __builtin_amdgcn_mfma_f32_32x32x16_bf16(Ah, B0l, d0, 0, 0, 0);
      d0 = __builtin_amdgcn_mfma_f32_32x32x16_bf16(Ah, B0h, d0, 0, 0, 0);
      d1 = __builtin_amdgcn_mfma_f32_32x32x16_bf16(Al, B1h, z, 0, 0, 0);
      d1 = __builtin_amdgcn_mfma_f32_32x32x16_bf16(Ah, B1l, d1, 0, 0, 0);
      d1 = __builtin_amdgcn_mfma_f32_32x32x16_bf16(Ah, B1h, d1, 0, 0, 0);
    }
    // D col = lane&31 (unit); 16 regs x 2 lane-halves tile the 32 rows.
    float mx0 = d0[0], mx1 = d1[0];
    float l0s = d0[0], l1s = d1[0];
    float l0q = d0[0] * d0[0], l1q = d1[0] * d1[0];
#pragma unroll
    for (int r = 1; r < 15; r += 2) {
      float a = d0[r], a2 = d0[r + 1], b = d1[r], b2 = d1[r + 1];
      mx0 = fmaxf(fmaxf(mx0, a), a2);        // fuses to v_max3_f32
      mx1 = fmaxf(fmaxf(mx1, b), b2);
      l0s += a + a2;  l1s += b + b2;
      l0q = fmaf(a, a, l0q);  l0q = fmaf(a2, a2, l0q);
      l1q = fmaf(b, b, l1q);  l1q = fmaf(b2, b2, l1q);
    }
    {
      float a = d0[15], b = d1[15];
      mx0 = fmaxf(mx0, a); mx1 = fmaxf(mx1, b);
      l0s += a; l1s += b;
      l0q = fmaf(a, a, l0q); l1q = fmaf(b, b, l1q);
    }
    sA0 += l0s; sQ0 += l0q; sA1 += l1s; sQ1 += l1q;
    mx0 = fmaxf(mx0, __shfl_xor(mx0, 32));
    mx1 = fmaxf(mx1, __shfl_xor(mx1, 32));
    float val = lo ? mx0 : mx1;              // unit index == lane
    _Float16 hf = (_Float16)val;
    int pq = chunk * 8 + wave * 2 + q;
    mm[(size_t)pq * 64 + lane] = __builtin_bit_cast(u16_t, hf);
  }
}

template<bool BF16>
__device__ __forceinline__ void fused_body(
    const void* __restrict__ feats, const int* __restrict__ nump,
    const int* __restrict__ coors,
    const uint4* __restrict__ wsB0hi, const uint4* __restrict__ wsB0lo,
    const uint4* __restrict__ wsB1hi, const uint4* __restrict__ wsB1lo,
    u16_t* __restrict__ mm, float* __restrict__ part, int g1) {
  __shared__ float red[4][128];
  int tid = threadIdx.x;
  int wave = tid >> 6, lane = tid & 63;
  int pp = (lane >> 5) & 1, m = lane & 31;
  bool lo = (lane < 32);

  bf16x8 B0h = __builtin_bit_cast(bf16x8, wsB0hi[lane]);
  bf16x8 B1h = __builtin_bit_cast(bf16x8, wsB1hi[lane]);
  bf16x8 B0l, B1l;
  if constexpr (!BF16) {
    B0l = __builtin_bit_cast(bf16x8, wsB0lo[lane]);
    B1l = __builtin_bit_cast(bf16x8, wsB1lo[lane]);
  }
  float sA0 = 0.0f, sQ0 = 0.0f, sA1 = 0.0f, sQ1 = 0.0f;  // Sum y', Sum y'^2

  // 2-chunk software pipeline: issue BOTH chunks' global loads before either
  // compute chain; chunk B's HBM latency hides under chunk A's compute.
  for (int chunk = blockIdx.x; chunk < NCHUNK; chunk += 2 * g1) {
    int cB = chunk + g1;
    bool hasB = (cB < NCHUNK);
    RawPt ra = load_raw<BF16>(feats, nump, coors, chunk * 8 + wave * 2 + pp, m);
    RawPt rb;
    if (hasB)
      rb = load_raw<BF16>(feats, nump, coors, cB * 8 + wave * 2 + pp, m);
    process_chunk<BF16>(ra, chunk, wave, lane, m, lo, B0h, B1h, B0l, B1l,
                        mm, sA0, sQ0, sA1, sQ1);
    if (hasB)
      process_chunk<BF16>(rb, cB, wave, lane, m, lo, B0h, B1h, B0l, B1l,
                          mm, sA0, sQ0, sA1, sQ1);
  }

  // block reduce: cols 0..63 = Sum y'_u, 64..127 = Sum y'_u^2
  sA0 += __shfl_xor(sA0, 32); sQ0 += __shfl_xor(sQ0, 32);
  sA1 += __shfl_xor(sA1, 32); sQ1 += __shfl_xor(sQ1, 32);
  if (lane < 32) {
    red[wave][lane]      = sA0;
    red[wave][32 + lane] = sA1;
    red[wave][64 + lane] = sQ0;
    red[wave][96 + lane] = sQ1;
  }
  __syncthreads();
  if (tid < 128)
    part[(size_t)tid * g1 + blockIdx.x] =
        red[0][tid] + red[1][tid] + red[2][tid] + red[3][tid];
}

__global__ __launch_bounds__(256, 4) void k_fused_all(
    const void* __restrict__ feats, const int* __restrict__ nump,
    const int* __restrict__ coors, const int* __restrict__ flag,
    const uint4* __restrict__ wsB0hi, const uint4* __restrict__ wsB0lo,
    const uint4* __restrict__ wsB1hi, const uint4* __restrict__ wsB1lo,
    u16_t* __restrict__ mm, float* __restrict__ part, int g1) {
  if (*flag)  // uniform
    fused_body<true >(feats, nump, coors, wsB0hi, wsB0lo, wsB1hi, wsB1lo, mm, part, g1);
  else
    fused_body<false>(feats, nump, coors, wsB0hi, wsB0lo, wsB1hi, wsB1lo, mm, part, g1);
}

__global__ void k_reduce2(const float* __restrict__ part,
                          double* __restrict__ mom, int g1) {
  int j = blockIdx.x, tid = threadIdx.x;   // 128 blocks
  double s = 0.0;
  for (int b = tid; b < g1; b += 256) s += (double)part[(size_t)j * g1 + b];
  __shared__ double red[256];
  red[tid] = s;
  __syncthreads();
  for (int off = 128; off; off >>= 1) {
    if (tid < off) red[tid] += red[tid + off];
    __syncthreads();
  }
  if (tid == 0) mom[j] = red[0];
}

__global__ void k_fin2_all(const double* __restrict__ mom,
                           const void* __restrict__ gamma,
                           const void* __restrict__ beta,
                           const int* __restrict__ flag,
                           float* __restrict__ wsS, float* __restrict__ wsT) {
  int u = threadIdx.x;  // 64
  int bf = *flag;
  double mu  = mom[u] / CNT_TOT;               // mean of y' = sgn*y
  double var = mom[64 + u] / CNT_TOT - mu * mu;
  float g  = bf ? ldval<true>(gamma, u) : ldval<false>(gamma, u);
  float be = bf ? ldval<true>(beta,  u) : ldval<false>(beta,  u);
  float S = (float)(1.0 / sqrt(var + 1e-3)) * fabsf(g);  // |gamma| absorbs sgn
  float T = be - (float)mu * S;
  wsS[u] = S;
  wsT[u] = T;
}

// out_u = relu(S*max + T). 25.6 MB in + 25.6/51.2 MB out.
__global__ __launch_bounds__(256) void k_out_all(
    const uint4* __restrict__ mm4, const float* __restrict__ wsS,
    const float* __restrict__ wsT, const int* __restrict__ flag,
    void* __restrict__ outv) {
  __shared__ float sS[64], sT[64];
  int tid = threadIdx.x;
  int bf = *flag;
  if (tid < 64) { sS[tid] = wsS[tid]; sT[tid] = wsT[tid]; }
  __syncthreads();
  const int total = N_P * 8;   // uint4 count (8 units each)
  for (int i = blockIdx.x * 256 + tid; i < total; i += gridDim.x * 256) {
    uint4 v = mm4[i];
    unsigned w[4] = {v.x, v.y, v.z, v.w};
    int u0 = (i & 7) * 8;
    float o[8];
#pragma unroll
    for (int j = 0; j < 4; ++j) {
      float mxa = h2lo(w[j]), mxb = h2hi(w[j]);
      o[2 * j]     = fmaxf(fmaf(sS[u0 + 2 * j],     mxa, sT[u0 + 2 * j]),     0.0f);
      o[2 * j + 1] = fmaxf(fmaf(sS[u0 + 2 * j + 1], mxb, sT[u0 + 2 * j + 1]), 0.0f);
    }
    if (bf) {
      uint4 r;
      r.x = packbf(o[0], o[1]); r.y = packbf(o[2], o[3]);
      r.z = packbf(o[4], o[5]); r.w = packbf(o[6], o[7]);
      ((uint4*)outv)[i] = r;
    } else {
      float4 f0, f1;
      f0.x = o[0]; f0.y = o[1]; f0.z = o[2]; f0.w = o[3];
      f1.x = o[4]; f1.y = o[5]; f1.z = o[6]; f1.w = o[7];
      ((float4*)outv)[i * 2]     = f0;
      ((float4*)outv)[i * 2 + 1] = f1;
    }
  }
}

// ============================ FALLBACK PATH ================================
// (two-pass pipeline; wsS = |S| and B pre-flipped keep k_main correct)

__global__ void k_detect(const u16_t* __restrict__ f, int* __restrict__ flag) {
  int tid = threadIdx.x;  // 64
  int cnt = 0;
  for (int i = 0; i < 4; ++i) {
    unsigned v = f[(size_t)(tid * 4 + i) * 2];
    unsigned e = (v >> 7) & 0xFF;
    cnt += (e >= 100 && e <= 140) ? 1 : 0;
  }
  for (int s = 1; s < 64; s <<= 1) cnt += __shfl_xor(cnt, s);
  if (tid == 0) *flag = (cnt >= 160) ? 1 : 0;   // 1 == bf16
}

template<bool BF16>
__device__ __forceinline__ void derive_feat(
    const void* __restrict__ feats, const int* __restrict__ nump,
    const int* __restrict__ coors, int p, int m, float* feat) {
  RawPt R = load_raw<BF16>(feats, nump, coors, p, m);
  float sx = R.r[0], sy = R.r[1], sz = R.r[2], svx = R.r[3], svy = R.r[4];
#pragma unroll
  for (int sft = 1; sft < 32; sft <<= 1) {
    sx  += __shfl_xor(sx,  sft);
    sy  += __shfl_xor(sy,  sft);
    sz  += __shfl_xor(sz,  sft);
    svx += __shfl_xor(svx, sft);
    svy += __shfl_xor(svy, sft);
  }
  float inv = 1.0f / (float)R.np;
  feat[0] = R.r[0] - R.cx;
  feat[1] = R.r[1] - R.cy;
  feat[2] = R.r[2]; feat[3] = R.r[3]; feat[4] = R.r[4];
  feat[5] = R.r[5]; feat[6] = R.r[6]; feat[7] = R.r[7]; feat[8] = R.r[8];
  feat[9]  = R.r[0] - sx * inv;
  feat[10] = R.r[1] - sy * inv;
  feat[11] = R.r[2] - sz * inv;
  feat[12] = feat[0];
  feat[13] = feat[1];
  feat[14] = R.r[3] - svx * inv;
  feat[15] = R.r[4] - svy * inv;
  if (m >= R.np) {
#pragma unroll
    for (int c = 0; c < 16; ++c) feat[c] = 0.0f;
  }
}

template<bool BF16>
__global__ void k_moments(const void* __restrict__ feats,
                          const int* __restrict__ nump,
                          const int* __restrict__ coors,
                          const int* __restrict__ flag,
                          float* __restrict__ part, int g1) {
  if (*flag != (BF16 ? 1 : 0)) return;
  int tid = threadIdx.x;
  int wave = tid >> 6, lane = tid & 63;
  int pp = (lane >> 5) & 1, m = lane & 31;
  float acc[68];
#pragma unroll
  for (int i = 0; i < 68; ++i) acc[i] = 0.0f;

  for (int chunk = blockIdx.x; chunk < NCHUNK; chunk += g1) {
    int p = chunk * 8 + wave * 2 + pp;
    float feat[16];
    derive_feat<BF16>(feats, nump, coors, p, m, feat);
#pragma unroll
    for (int c = 0; c < 16; ++c) acc[c] += feat[c];
#pragma unroll
    for (int t = 0; t < 52; ++t)
      acc[16 + t] = fmaf(feat[PT.pi[t]], feat[PT.pj[t]], acc[16 + t]);
  }

#pragma unroll
  for (int k = 0; k < 68; ++k) {
    float v = acc[k];
#pragma unroll
    for (int sft = 1; sft < 64; sft <<= 1) v += __shfl_xor(v, sft);
    acc[k] = v;
  }
  __shared__ float red[4][68];
  if (lane == 0) {
#pragma unroll
    for (int k = 0; k < 68; ++k) red[wave][k] = acc[k];
  }
  __syncthreads();
  if (tid < 68) {
    float t = red[0][tid] + red[1][tid] + red[2][tid] + red[3][tid];
    part[(size_t)tid * g1 + blockIdx.x] = t;
  }
}

__global__ void k_reduce(const float* __restrict__ part,
                         float* __restrict__ mom, int g1) {
  int j = blockIdx.x, tid = threadIdx.x;
  float s = 0.0f;
  for (int b = tid; b < g1; b += 256) s += part[(size_t)j * g1 + b];
  __shared__ float red[256];
  red[tid] = s;
  __syncthreads();
  for (int off = 128; off; off >>= 1) {
    if (tid < off) red[tid] += red[tid + off];
    __syncthreads();
  }
  if (tid == 0) mom[j] = red[0];
}

template<bool BF16>
__global__ void k_finalize(const float* __restrict__ mom,
    const void* __restrict__ w1, const void* __restrict__ w2,
    const void* __restrict__ w3, const void* __restrict__ w4,
    const void* __restrict__ gamma, const void* __restrict__ beta,
    const int* __restrict__ flag,
    float* __restrict__ wsS, float* __restrict__ wsT,
    uint4* __restrict__ wsB0hi, uint4* __restrict__ wsB0lo,
    uint4* __restrict__ wsB1hi, uint4* __restrict__ wsB1lo) {
  if (*flag != (BF16 ? 1 : 0)) return;
  int u = threadIdx.x;  // 0..63
  const int CHOFF[4] = {0, 8, 10, 12};
  const int CCNT[4]  = {8, 2, 2, 4};
  const int LCH[16]  = {0,1,2,5,6,7,8,9, 3,10, 4,11, 12,13,14,15};
  const int PBASE[4] = {0, 36, 39, 42};
  const int PCNTB[4] = {36, 3, 3, 10};

  int b = u >> 4, k = u & 15;
  const void* wsrc = (b == 0) ? w1 : (b == 1) ? w2 : (b == 2) ? w3 : w4;
  int cc = CCNT[b];
  float  w[8];
  double mf[8];
  for (int i = 0; i < 8; ++i) { w[i] = 0.0f; mf[i] = 0.0; }
  for (int i = 0; i < cc; ++i) {
    w[i]  = ldval<BF16>(wsrc, k * cc + i);
    mf[i] = (double)mom[LCH[CHOFF[b] + i]] / CNT_TOT;
  }
  double mu = 0.0;
  for (int i = 0; i < cc; ++i) mu += (double)w[i] * mf[i];
  double var = 0.0;
  for (int t = 0; t < PCNTB[b]; ++t) {
    int idx = PBASE[b] + t;
    int a = PT.pa[idx], b2 = PT.pb[idx];
    double e2  = (double)mom[16 + idx] / CNT_TOT;
    double cov = e2 - mf[a] * mf[b2];
    var += ((a == b2) ? 1.0 : 2.0) * (double)w[a] * (double)w[b2] * cov;
  }
  float g  = ldval<BF16>(gamma, u);
  float be = ldval<BF16>(beta, u);
  float S = (float)(1.0 / sqrt(var + 1e-3)) * g;
  float T = be - (float)mu * S;
  wsS[u] = fabsf(S);           // |S|: pairs with sign-flipped B frags
  wsT[u] = T;

  pack_frags<BF16>(u, w1, w2, w3, w4, gamma, wsB0hi, wsB0lo, wsB1hi, wsB1lo);
}

template<bool BF16>
__global__ __launch_bounds__(256) void k_main(
    const void* __restrict__ feats, const int* __restrict__ nump,
    const int* __restrict__ coors, const int* __restrict__ flag,
    const float* __restrict__ wsS, const float* __restrict__ wsT,
    const uint4* __restrict__ wsB0hi, const uint4* __restrict__ wsB0lo,
    const uint4* __restrict__ wsB1hi, const uint4* __restrict__ wsB1lo,
    void* __restrict__ outv) {
  if (*flag != (BF16 ? 1 : 0)) return;
  constexpr int TILE = 8 * 32 * 3;
  __shared__ uint4 featL[(BF16 ? 1 : 2) * TILE];
  int tid = threadIdx.x;
  int wave = tid >> 6, lane = tid & 63;
  int pp = (lane >> 5) & 1, m = lane & 31;

  bf16x8 B0h = __builtin_bit_cast(bf16x8, wsB0hi[lane]);
  bf16x8 B1h = __builtin_bit_cast(bf16x8, wsB1hi[lane]);
  bf16x8 B0l, B1l;
  if constexpr (!BF16) {
    B0l = __builtin_bit_cast(bf16x8, wsB0lo[lane]);
    B1l = __builtin_bit_cast(bf16x8, wsB1lo[lane]);
  }
  int ucol = lane & 31;
  float s0 = wsS[ucol],      t0 = wsT[ucol];
  float s1 = wsS[ucol + 32], t1 = wsT[ucol + 32];

  int wp = wave * 2 + pp;
  int p  = blockIdx.x * 8 + wp;
  float feat[16];
  derive_feat<BF16>(feats, nump, coors, p, m, feat);

  unsigned pkh[8], pkl[8];
#pragma unroll
  for (int j = 0; j < 8; ++j) {
    float a0 = feat[2 * j], a1 = feat[2 * j + 1];
    u16_t h0 = f2bf(a0), h1 = f2bf(a1);
    pkh[j] = (unsigned)h0 | ((unsigned)h1 << 16);
    if constexpr (!BF16) {
      u16_t q0 = f2bf(a0 - bf2f(h0)), q1 = f2bf(a1 - bf2f(h1));
      pkl[j] = (unsigned)q0 | ((unsigned)q1 << 16);
    }
  }
  uint4 v;
  v.x = pkh[0]; v.y = pkh[1]; v.z = pkh[2]; v.w = pkh[3];
  featL[(wp * 32 + m) * 3 + 0] = v;
  v.x = pkh[4]; v.y = pkh[5]; v.z = pkh[6]; v.w = pkh[7];
  featL[(wp * 32 + m) * 3 + 1] = v;
  if constexpr (!BF16) {
    v.x = pkl[0]; v.y = pkl[1]; v.z = pkl[2]; v.w = pkl[3];
    featL[TILE + (wp * 32 + m) * 3 + 0] = v;
    v.x = pkl[4]; v.y = pkl[5]; v.z = pkl[6]; v.w = pkl[7];
    featL[TILE + (wp * 32 + m) * 3 + 1] = v;
  }
  __syncthreads();

  floatx16 z;
#pragma unroll
  for (int i = 0; i < 16; ++i) z[i] = 0.0f;

#pragma unroll
  for (int q = 0; q < 2; ++q) {
    int wq = wave * 2 + q;
    int ridx = (wq * 32 + (lane & 31)) * 3 + (lane >> 5);
    bf16x8 Ah = __builtin_bit_cast(bf16x8, featL[ridx]);
    floatx16 d0, d1;
    if constexpr (BF16) {
      d0 = __builtin_amdgcn_mfma_f32_32x32x16_bf16(Ah, B0h, z, 0, 0, 0);
      d1 = __builtin_amdgcn_mfma_f32_32x32x16_bf16(Ah, B1h, z, 0, 0, 0);
    } else {
      bf16x8 Al = __builtin_bit_cast(bf16x8, featL[TILE + ridx]);
      d0 = __builtin_amdgcn_mfma_f32_32x32x16_bf16(Al, B0h, z, 0, 0, 0);
      d0 = __builtin_amdgcn_mfma_f32_32x32x16_bf16(Ah, B0l, d0, 0, 0, 0);
      d0 = __builtin_amdgcn_mfma_f32_32x32x16_bf16(Ah, B0h, d0, 0, 0, 0);
      d1 = __builtin_amdgcn_mfma_f32_32x32x16_bf16(Al, B1h, z, 0, 0, 0);
      d1 = __builtin_amdgcn_mfma_f32_32x32x16_bf16(Ah, B1l, d1, 0, 0, 0);
      d1 = __builtin_amdgcn_mfma_f32_32x32x16_bf16(Ah, B1h, d1, 0, 0, 0);
    }
    float mx0 = fmaf(d0[0], s0, t0);
    float mx1 = fmaf(d1[0], s1, t1);
#pragma unroll
    for (int r = 1; r < 16; ++r) {
      mx0 = fmaxf(mx0, fmaf(d0[r], s0, t0));
      mx1 = fmaxf(mx1, fmaf(d1[r], s1, t1));
    }
    mx0 = fmaxf(mx0, __shfl_xor(mx0, 32));
    mx1 = fmaxf(mx1, __shfl_xor(mx1, 32));
    mx0 = fmaxf(mx0, 0.0f);
    mx1 = fmaxf(mx1, 0.0f);
    float val = (lane < 32) ? mx0 : mx1;
    size_t oidx = (size_t)(blockIdx.x * 8 + wq) * 64 + lane;
    if constexpr (BF16) ((u16_t*)outv)[oidx] = f2bf(val);
    else                ((float*)outv)[oidx] = val;
  }
}

// ---------------------------------------------------------------------------
extern "C" void kernel_launch(void* const* d_in, const int* in_sizes, int n_in,
                              void* d_out, int out_size, void* d_ws, size_t ws_size,
                              hipStream_t stream) {
  (void)in_sizes; (void)n_in; (void)out_size;
  const void* feats = d_in[0];
  const void* w1    = d_in[1];
  const void* w2    = d_in[2];
  const void* w3    = d_in[3];
  const void* w4    = d_in[4];
  const void* gamma = d_in[5];
  const void* beta  = d_in[6];
  const int*  nump  = (const int*)d_in[7];
  const int*  coors = (const int*)d_in[8];

  char* ws = (char*)d_ws;
  int*   flag   = (int*)(ws + 0);
  float* wsS    = (float*)(ws + 64);      // 64 f32
  float* wsT    = (float*)(ws + 320);     // 64 f32
  uint4* wsB0hi = (uint4*)(ws + 576);     // 64 x 16B
  uint4* wsB0lo = (uint4*)(ws + 1600);
  uint4* wsB1hi = (uint4*)(ws + 2624);
  uint4* wsB1lo = (uint4*)(ws + 3648);

  // fused-path layout
  const int g1f = 2048;
  double* mom2  = (double*)(ws + 4672);             // 128 f64 -> 5696
  float*  part2 = (float*)(ws + 5696);              // 128*2048*4 = 1 MiB
  u16_t*  mm    = (u16_t*)(ws + 1054336);           // N*64*2B = 25.6 MB
  size_t need_fused = 1054336ull + (size_t)N_P * 64ull * 2ull;

  if (ws_size >= need_fused) {
    k_init<<<1, 64, 0, stream>>>(feats, w1, w2, w3, w4, gamma, flag,
                                 wsB0hi, wsB0lo, wsB1hi, wsB1lo);
    k_fused_all<<<g1f, 256, 0, stream>>>(feats, nump, coors, flag,
                                         wsB0hi, wsB0lo, wsB1hi, wsB1lo,
                                         mm, part2, g1f);
    k_reduce2<<<128, 256, 0, stream>>>(part2, mom2, g1f);
    k_fin2_all<<<1, 64, 0, stream>>>(mom2, gamma, beta, flag, wsS, wsT);
    k_out_all<<<2048, 256, 0, stream>>>((const uint4*)mm, wsS, wsT, flag, d_out);
    return;
  }

  // -------- fallback: two-pass pipeline --------
  float* mom  = (float*)(ws + 4672);    // 68 f32
  float* part = (float*)(ws + 5120);    // 68 x g1 f32

  int g1 = 1024;
  size_t need = 5120 + (size_t)68 * (size_t)g1 * 4;
  if (need > ws_size) {
    size_t avail = (ws_size > 5120) ? (ws_size - 5120) : 0;
    g1 = (int)(avail / (68 * 4));
    if (g1 > 1024) g1 = 1024;
    if (g1 < 8) g1 = 8;
  }

  k_detect<<<1, 64, 0, stream>>>((const u16_t*)feats, flag);
  k_moments<true ><<<g1, 256, 0, stream>>>(feats, nump, coors, flag, part, g1);
  k_moments<false><<<g1, 256, 0, stream>>>(feats, nump, coors, flag, part, g1);
  k_reduce<<<68, 256, 0, stream>>>(part, mom, g1);
  k_finalize<true ><<<1, 64, 0, stream>>>(mom, w1, w2, w3, w4, gamma, beta, flag,
                                          wsS, wsT, wsB0hi, wsB0lo, wsB1hi, wsB1lo);
  k_finalize<false><<<1, 64, 0, stream>>>(mom, w1, w2, w3, w4, gamma, beta, flag,
                                          wsS, wsT, wsB0hi, wsB0lo, wsB1hi, wsB1lo);
  k_main<true ><<<N_P / 8, 256, 0, stream>>>(feats, nump, coors, flag, wsS, wsT,
                                             wsB0hi, wsB0lo, wsB1hi, wsB1lo, d_out);
  k_main<false><<<N_P / 8, 256, 0, stream>>>(feats, nump, coors, flag, wsS, wsT,
                                             wsB0hi, wsB0lo, wsB1hi, wsB1lo, d_out);
}